// Round 1
// baseline (864.964 us; speedup 1.0000x reference)
//
#include <hip/hip_runtime.h>

#define B_   4
#define N_   2048
#define HID  512
#define NH   8
#define HD   64
#define TOK  (B_ * N_)   // 8192

// ---------------------------------------------------------------------------
// GEMM (NT): C[i][j] = sum_k A[i][k] * W[j][k] + bias[j]
// A: TOK x HID row-major. W: HID x HID row-major (torch Linear weight).
// blockIdx.z selects (W,bias,C) triple so QKV runs as one launch.
// bhnd != 0: write C to (B, NH, N_, HD) layout; else plain row-major TOK x HID.
// Tile: 64x64, block 256 threads, 4x4 micro-tile. LDS stored k-major so the
// inner loop uses ds_read_b128.
// ---------------------------------------------------------------------------
__global__ __launch_bounds__(256) void gemm_nt(
    const float* __restrict__ A,
    const float* __restrict__ W0, const float* __restrict__ W1, const float* __restrict__ W2,
    const float* __restrict__ b0, const float* __restrict__ b1, const float* __restrict__ b2,
    float* __restrict__ C0, float* __restrict__ C1, float* __restrict__ C2,
    int bhnd)
{
    const float* W    = (blockIdx.z == 0) ? W0 : (blockIdx.z == 1) ? W1 : W2;
    const float* bias = (blockIdx.z == 0) ? b0 : (blockIdx.z == 1) ? b1 : b2;
    float*       C    = (blockIdx.z == 0) ? C0 : (blockIdx.z == 1) ? C1 : C2;

    __shared__ float As[16][64];   // [kk][row]
    __shared__ float Bs[16][64];   // [kk][col]

    const int tid = threadIdx.x;
    const int tx = tid & 15;       // col group
    const int ty = tid >> 4;       // row group
    const int row0 = blockIdx.x * 64;
    const int col0 = blockIdx.y * 64;

    // staging indices: each thread loads one float4 of A and one of W per k-tile
    const int lr = tid >> 2;            // 0..63
    const int lc = (tid & 3) * 4;       // 0,4,8,12

    float acc[4][4] = {};

    for (int k0 = 0; k0 < HID; k0 += 16) {
        const float4 av = *(const float4*)&A[(size_t)(row0 + lr) * HID + k0 + lc];
        const float4 wv = *(const float4*)&W[(size_t)(col0 + lr) * HID + k0 + lc];
        As[lc + 0][lr] = av.x; As[lc + 1][lr] = av.y; As[lc + 2][lr] = av.z; As[lc + 3][lr] = av.w;
        Bs[lc + 0][lr] = wv.x; Bs[lc + 1][lr] = wv.y; Bs[lc + 2][lr] = wv.z; Bs[lc + 3][lr] = wv.w;
        __syncthreads();

        #pragma unroll
        for (int kk = 0; kk < 16; ++kk) {
            float4 a4 = *(const float4*)&As[kk][ty * 4];
            float4 b4 = *(const float4*)&Bs[kk][tx * 4];
            float ar[4] = {a4.x, a4.y, a4.z, a4.w};
            float bc[4] = {b4.x, b4.y, b4.z, b4.w};
            #pragma unroll
            for (int r = 0; r < 4; ++r)
                #pragma unroll
                for (int c = 0; c < 4; ++c)
                    acc[r][c] += ar[r] * bc[c];
        }
        __syncthreads();
    }

    #pragma unroll
    for (int r = 0; r < 4; ++r) {
        const int i = row0 + ty * 4 + r;
        #pragma unroll
        for (int c = 0; c < 4; ++c) {
            const int j = col0 + tx * 4 + c;
            const float val = acc[r][c] + bias[j];
            if (bhnd) {
                const int b = i >> 11, n = i & (N_ - 1);
                const int h = j >> 6, d = j & (HD - 1);
                C[(((size_t)b * NH + h) * N_ + n) * HD + d] = val;
            } else {
                C[(size_t)i * HID + j] = val;
            }
        }
    }
}

// ---------------------------------------------------------------------------
// Flash attention (fp32). One block per (q-tile of 64 rows, b*NH+h).
// Q/K/V in (B,NH,N,HD). Output written in (B, N, HID) layout for the O-proj.
// Per-head cancer bias and keymod cancel in softmax (constant along axis -1).
// ---------------------------------------------------------------------------
__global__ __launch_bounds__(256) void flash_attn(
    const float* __restrict__ Q, const float* __restrict__ K,
    const float* __restrict__ V, const unsigned char* __restrict__ msk,
    float* __restrict__ AO)
{
    __shared__ float Qt[64][68];   // [d][row]
    __shared__ float Kt[64][68];   // [d][col]
    __shared__ float Vs[64][64];   // [j][d]
    __shared__ float Pt[64][68];   // [j][row]

    const int tid = threadIdx.x;
    const int tx = tid & 15, ty = tid >> 4;
    const int tx4 = tx * 4, ty4 = ty * 4;

    const int bh = blockIdx.y;
    const int b = bh >> 3, h = bh & 7;
    const int qrow0 = blockIdx.x * 64;

    const size_t headoff = ((size_t)b * NH + h) * N_ * HD;
    const float* Qh = Q + headoff;
    const float* Kh = K + headoff;
    const float* Vh = V + headoff;
    const unsigned char* mrow = msk + (size_t)b * N_;

    // stage Q tile transposed: thread (br=tid>>4, bc=tid&15) handles a 4x4 block
    const int br = ty, bc = tx;
    {
        float4 rowv[4];
        #pragma unroll
        for (int rr = 0; rr < 4; ++rr)
            rowv[rr] = *(const float4*)&Qh[(size_t)(qrow0 + br * 4 + rr) * HD + bc * 4];
        #pragma unroll
        for (int i = 0; i < 4; ++i) {
            float4 t;
            t.x = (&rowv[0].x)[i]; t.y = (&rowv[1].x)[i];
            t.z = (&rowv[2].x)[i]; t.w = (&rowv[3].x)[i];
            *(float4*)&Qt[bc * 4 + i][br * 4] = t;
        }
    }

    float m[4], l[4], o[4][4];
    #pragma unroll
    for (int r = 0; r < 4; ++r) { m[r] = -3.0e38f; l[r] = 0.f; }
    #pragma unroll
    for (int r = 0; r < 4; ++r)
        #pragma unroll
        for (int c = 0; c < 4; ++c) o[r][c] = 0.f;

    for (int kt = 0; kt < N_ / 64; ++kt) {
        __syncthreads();   // previous PV reads of Pt/Vs (and Q staging) complete

        // stage K tile transposed (same 4x4 scheme) and V tile direct
        {
            const int krow0 = kt * 64;
            float4 rowv[4];
            #pragma unroll
            for (int rr = 0; rr < 4; ++rr)
                rowv[rr] = *(const float4*)&Kh[(size_t)(krow0 + br * 4 + rr) * HD + bc * 4];
            #pragma unroll
            for (int i = 0; i < 4; ++i) {
                float4 t;
                t.x = (&rowv[0].x)[i]; t.y = (&rowv[1].x)[i];
                t.z = (&rowv[2].x)[i]; t.w = (&rowv[3].x)[i];
                *(float4*)&Kt[bc * 4 + i][br * 4] = t;
            }
            #pragma unroll
            for (int it = 0; it < 4; ++it) {
                const int idx = tid + it * 256;       // 0..1023
                const int row = idx >> 4, c4 = (idx & 15) * 4;
                *(float4*)&Vs[row][c4] =
                    *(const float4*)&Vh[(size_t)(krow0 + row) * HD + c4];
            }
        }
        __syncthreads();

        // S = Q K^T for this tile (registers), 4x4 per thread
        float s[4][4] = {};
        #pragma unroll 16
        for (int kk = 0; kk < 64; ++kk) {
            float4 a4 = *(const float4*)&Qt[kk][ty4];
            float4 b4 = *(const float4*)&Kt[kk][tx4];
            float ar[4] = {a4.x, a4.y, a4.z, a4.w};
            float bc4[4] = {b4.x, b4.y, b4.z, b4.w};
            #pragma unroll
            for (int r = 0; r < 4; ++r)
                #pragma unroll
                for (int c = 0; c < 4; ++c)
                    s[r][c] += ar[r] * bc4[c];
        }

        // scale + mask
        #pragma unroll
        for (int c = 0; c < 4; ++c) {
            const int jg = kt * 64 + tx4 + c;
            const bool masked = mrow[jg] != 0;
            #pragma unroll
            for (int r = 0; r < 4; ++r)
                s[r][c] = masked ? -3.0e38f : s[r][c] * 0.125f;
        }

        // online softmax update (row groups live in the tx dimension: lanes
        // xor 1,2,4,8 stay inside the 16-lane row group of the wave)
        #pragma unroll
        for (int r = 0; r < 4; ++r) {
            float tm = fmaxf(fmaxf(s[r][0], s[r][1]), fmaxf(s[r][2], s[r][3]));
            tm = fmaxf(tm, __shfl_xor(tm, 1));
            tm = fmaxf(tm, __shfl_xor(tm, 2));
            tm = fmaxf(tm, __shfl_xor(tm, 4));
            tm = fmaxf(tm, __shfl_xor(tm, 8));
            const float mnew = fmaxf(m[r], tm);
            const float alpha = __expf(m[r] - mnew);
            float rs = 0.f;
            #pragma unroll
            for (int c = 0; c < 4; ++c) { s[r][c] = __expf(s[r][c] - mnew); rs += s[r][c]; }
            rs += __shfl_xor(rs, 1);
            rs += __shfl_xor(rs, 2);
            rs += __shfl_xor(rs, 4);
            rs += __shfl_xor(rs, 8);
            l[r] = l[r] * alpha + rs;
            m[r] = mnew;
            #pragma unroll
            for (int c = 0; c < 4; ++c) o[r][c] *= alpha;
        }

        // write P transposed to LDS: Pt[col j][row i]
        #pragma unroll
        for (int c = 0; c < 4; ++c) {
            float4 t = make_float4(s[0][c], s[1][c], s[2][c], s[3][c]);
            *(float4*)&Pt[tx4 + c][ty4] = t;
        }
        __syncthreads();

        // O += P V : o[r][c] over rows ty4+r, dims tx4+c
        #pragma unroll 8
        for (int j = 0; j < 64; ++j) {
            float4 p4 = *(const float4*)&Pt[j][ty4];
            float4 v4 = *(const float4*)&Vs[j][tx4];
            float pr[4] = {p4.x, p4.y, p4.z, p4.w};
            float vc[4] = {v4.x, v4.y, v4.z, v4.w};
            #pragma unroll
            for (int r = 0; r < 4; ++r)
                #pragma unroll
                for (int c = 0; c < 4; ++c)
                    o[r][c] += pr[r] * vc[c];
        }
    }

    // epilogue: normalize and write to (B, N, HID) layout
    #pragma unroll
    for (int r = 0; r < 4; ++r) {
        const int n = qrow0 + ty4 + r;
        const float inv = 1.0f / l[r];
        float4 t = make_float4(o[r][0] * inv, o[r][1] * inv, o[r][2] * inv, o[r][3] * inv);
        *(float4*)&AO[((size_t)b * N_ + n) * HID + h * HD + tx4] = t;
    }
}

// ---------------------------------------------------------------------------
extern "C" void kernel_launch(void* const* d_in, const int* in_sizes, int n_in,
                              void* d_out, int out_size, void* d_ws, size_t ws_size,
                              hipStream_t stream) {
    const float* x  = (const float*)d_in[0];
    // d_in[1] = cancer_type (unused: bias/keymod are constant along softmax axis)
    const unsigned char* mask = (const unsigned char*)d_in[2];  // all-false in test
    const float* wq = (const float*)d_in[3];
    const float* bq = (const float*)d_in[4];
    const float* wk = (const float*)d_in[5];
    const float* bk = (const float*)d_in[6];
    const float* wv = (const float*)d_in[7];
    const float* bv = (const float*)d_in[8];
    const float* wo = (const float*)d_in[9];
    const float* bo = (const float*)d_in[10];
    // d_in[11] = bias_emb, d_in[12] = keymod_emb: mathematically no-ops

    float* out = (float*)d_out;
    float* ws  = (float*)d_ws;
    const size_t per = (size_t)B_ * NH * N_ * HD;   // 4 Mi floats = 16 MB
    float* q  = ws;
    float* k  = ws + per;
    float* v  = ws + 2 * per;
    float* ao = ws + 3 * per;

    // QKV projections (one launch, z selects weight)
    gemm_nt<<<dim3(TOK / 64, HID / 64, 3), 256, 0, stream>>>(
        x, wq, wk, wv, bq, bk, bv, q, k, v, 1);

    // attention
    flash_attn<<<dim3(N_ / 64, B_ * NH), 256, 0, stream>>>(q, k, v, mask, ao);

    // output projection
    gemm_nt<<<dim3(TOK / 64, HID / 64, 1), 256, 0, stream>>>(
        ao, wo, wo, wo, bo, bo, bo, out, out, out, 0);
}

// Round 2
// 297.401 us; speedup vs baseline: 2.9084x; 2.9084x over previous
//
#include <hip/hip_runtime.h>

#define B_    4
#define N_    2048
#define HID   512
#define NH    8
#define HD    64
#define TOK   (B_ * N_)   // 8192

typedef __attribute__((ext_vector_type(8))) short short8;
typedef __attribute__((ext_vector_type(4))) float f32x4;
typedef unsigned short u16;

// fp32 -> bf16 round-to-nearest-even (values are finite; no NaN handling needed)
static __device__ __forceinline__ u16 f2bf(float f) {
    unsigned int u = __builtin_bit_cast(unsigned int, f);
    u += 0x7FFFu + ((u >> 16) & 1u);
    return (u16)(u >> 16);
}

// ---------------------------------------------------------------------------
// fp32 -> bf16 converters
// ---------------------------------------------------------------------------
__global__ __launch_bounds__(256) void cvt_x(const float* __restrict__ src,
                                             u16* __restrict__ dst) {
    const int i = (blockIdx.x * 256 + threadIdx.x) * 4;
    const float4 v = *(const float4*)&src[i];
    ushort4 o;
    o.x = f2bf(v.x); o.y = f2bf(v.y); o.z = f2bf(v.z); o.w = f2bf(v.w);
    *(ushort4*)&dst[i] = o;
}

__global__ __launch_bounds__(256) void cvt_w(
    const float* __restrict__ w0, const float* __restrict__ w1,
    const float* __restrict__ w2, const float* __restrict__ w3,
    u16* __restrict__ d0, u16* __restrict__ d1,
    u16* __restrict__ d2, u16* __restrict__ d3) {
    const float* s = blockIdx.y == 0 ? w0 : blockIdx.y == 1 ? w1 : blockIdx.y == 2 ? w2 : w3;
    u16*        d  = blockIdx.y == 0 ? d0 : blockIdx.y == 1 ? d1 : blockIdx.y == 2 ? d2 : d3;
    const int i = (blockIdx.x * 256 + threadIdx.x) * 4;
    const float4 v = *(const float4*)&s[i];
    ushort4 o;
    o.x = f2bf(v.x); o.y = f2bf(v.y); o.z = f2bf(v.z); o.w = f2bf(v.w);
    *(ushort4*)&d[i] = o;
}

// ---------------------------------------------------------------------------
// bf16 MFMA GEMM (NT): C[i][j] = sum_k A[i][k]*W[j][k] + bias[j]
// 128x128 tile, BK=32, 256 threads = 4 waves in 2x2, each wave 64x64 (4x4 frags
// of 16x16x32). qkv=1: z0/z1 -> (B,NH,N,HD) bf16; z2 -> permuted V^T
// (B,NH,HD,N') bf16 with n' = tilebase + (key%16)*4 + key/16 (key = n%64).
// qkv=0: fp32 flat [TOK][HID] out.
// ---------------------------------------------------------------------------
__global__ __launch_bounds__(256) void gemm_mfma(
    const u16* __restrict__ A,
    const u16* __restrict__ W0, const u16* __restrict__ W1, const u16* __restrict__ W2,
    const float* __restrict__ bias0, const float* __restrict__ bias1, const float* __restrict__ bias2,
    void* __restrict__ C0, void* __restrict__ C1, void* __restrict__ C2,
    int qkv)
{
    const int z = blockIdx.z;
    const u16*   W    = z == 0 ? W0 : z == 1 ? W1 : W2;
    const float* bias = z == 0 ? bias0 : z == 1 ? bias1 : bias2;

    __shared__ u16 As[128][32];
    __shared__ u16 Bs[128][32];

    const int tid  = threadIdx.x;
    const int row0 = blockIdx.x * 128, col0 = blockIdx.y * 128;
    const int w    = tid >> 6, lane = tid & 63;
    const int wr   = w >> 1, wc = w & 1;
    const int t16  = lane & 15, q4 = lane >> 4;

    // staging: lane t writes 16B chunk (m = t>>2 (+64), kchunk = t&3) -> linear LDS
    const int sm = tid >> 2, sc = (tid & 3) * 8;

    f32x4 acc[4][4];
    #pragma unroll
    for (int mt = 0; mt < 4; ++mt)
        #pragma unroll
        for (int nt = 0; nt < 4; ++nt)
            acc[mt][nt] = (f32x4){0.f, 0.f, 0.f, 0.f};

    for (int k0 = 0; k0 < HID; k0 += 32) {
        __syncthreads();
        #pragma unroll
        for (int p = 0; p < 2; ++p) {
            const int m = sm + 64 * p;
            *(short8*)&As[m][sc] = *(const short8*)&A[(size_t)(row0 + m) * HID + k0 + sc];
            *(short8*)&Bs[m][sc] = *(const short8*)&W[(size_t)(col0 + m) * HID + k0 + sc];
        }
        __syncthreads();

        short8 af[4], bf[4];
        #pragma unroll
        for (int mt = 0; mt < 4; ++mt)
            af[mt] = *(const short8*)&As[wr * 64 + mt * 16 + t16][q4 * 8];
        #pragma unroll
        for (int nt = 0; nt < 4; ++nt)
            bf[nt] = *(const short8*)&Bs[wc * 64 + nt * 16 + t16][q4 * 8];
        #pragma unroll
        for (int mt = 0; mt < 4; ++mt)
            #pragma unroll
            for (int nt = 0; nt < 4; ++nt)
                acc[mt][nt] = __builtin_amdgcn_mfma_f32_16x16x32_bf16(
                    af[mt], bf[nt], acc[mt][nt], 0, 0, 0);
    }

    // epilogue: C/D layout row = q4*4 + reg, col = t16
    #pragma unroll
    for (int nt = 0; nt < 4; ++nt) {
        const int j  = col0 + wc * 64 + nt * 16 + t16;
        const float bv = bias[j];
        const int h = j >> 6, d = j & 63;
        #pragma unroll
        for (int mt = 0; mt < 4; ++mt) {
            #pragma unroll
            for (int r = 0; r < 4; ++r) {
                const int   i   = row0 + wr * 64 + mt * 16 + q4 * 4 + r;
                const float val = acc[mt][nt][r] + bv;
                if (!qkv) {
                    ((float*)C0)[(size_t)i * HID + j] = val;
                } else {
                    const int b = i >> 11, n = i & (N_ - 1);
                    if (z < 2) {
                        u16* C = (u16*)(z == 0 ? C0 : C1);
                        C[(((size_t)(b * NH + h)) * N_ + n) * HD + d] = f2bf(val);
                    } else {
                        u16* C = (u16*)C2;
                        const int nn = (n & ~63) | ((n & 15) * 4) | ((n >> 4) & 3);
                        C[(((size_t)(b * NH + h)) * HD + d) * N_ + nn] = f2bf(val);
                    }
                }
            }
        }
    }
}

// ---------------------------------------------------------------------------
// MFMA flash attention. Block = 256 threads (4 waves), 128 Q-rows per block
// (32 rows per wave = 2 m-tiles). K staged [key][d], V^T staged [d][c] where
// c is the permuted key order matching the P fragment packing:
// Ps column c = t16*4 + f  <->  key = f*16 + t16  <->  key = (c%4)*16 + c/4.
// Per-head cancer bias / keymod cancel in softmax (constant along key axis).
// ---------------------------------------------------------------------------
__global__ __launch_bounds__(256) void flash_mfma(
    const u16* __restrict__ Qg, const u16* __restrict__ Kg,
    const u16* __restrict__ Vtg, const unsigned char* __restrict__ msk,
    u16* __restrict__ AOg)
{
    __shared__ u16 Ks[64][72];     // [key][d], stride 144B -> optimal phases
    __shared__ u16 Vts[64][72];    // [d][c]
    __shared__ u16 Ps[4][32][72];  // per-wave P strip [row][c]

    const int tid = threadIdx.x;
    const int w = tid >> 6, lane = tid & 63;
    const int t16 = lane & 15, q4 = lane >> 4;
    const int bh = blockIdx.y, b = bh >> 3, h = bh & 7;
    const int qrow0 = blockIdx.x * 128;

    const size_t hb = (size_t)bh * N_ * HD;
    const u16* Qh  = Qg + hb;
    const u16* Kh  = Kg + hb;
    const u16* Vth = Vtg + hb;     // [d][n'] layout
    const unsigned char* mrow = msk + b * N_;

    // Q fragments, direct from global (A-layout: m = t16, k = q4*8+j)
    short8 qf[2][2];
    #pragma unroll
    for (int mt = 0; mt < 2; ++mt)
        #pragma unroll
        for (int kk = 0; kk < 2; ++kk)
            qf[mt][kk] = *(const short8*)
                &Qh[(size_t)(qrow0 + w * 32 + mt * 16 + t16) * HD + kk * 32 + q4 * 8];

    float m_[2][4], l_[2][4];
    f32x4 o[2][4];
    #pragma unroll
    for (int mt = 0; mt < 2; ++mt) {
        #pragma unroll
        for (int r = 0; r < 4; ++r) { m_[mt][r] = -3.0e38f; l_[mt][r] = 0.f; }
        #pragma unroll
        for (int nt = 0; nt < 4; ++nt) o[mt][nt] = (f32x4){0.f, 0.f, 0.f, 0.f};
    }

    const int sr = tid >> 3, scc = (tid & 7) * 8;  // staging row / col-chunk

    for (int kt = 0; kt < N_ / 64; ++kt) {
        __syncthreads();
        {
            const int kb = kt * 64;
            #pragma unroll
            for (int p = 0; p < 2; ++p) {
                const int rr = sr + 32 * p;
                *(short8*)&Ks[rr][scc]  = *(const short8*)&Kh[(size_t)(kb + rr) * HD + scc];
                *(short8*)&Vts[rr][scc] = *(const short8*)&Vth[(size_t)rr * N_ + kb + scc];
            }
        }
        __syncthreads();

        // S = Q K^T : B-frag = K rows (key = f*16 + t16, d = kk*32 + q4*8 + j)
        f32x4 s[2][4];
        #pragma unroll
        for (int mt = 0; mt < 2; ++mt)
            #pragma unroll
            for (int f = 0; f < 4; ++f)
                s[mt][f] = (f32x4){0.f, 0.f, 0.f, 0.f};
        #pragma unroll
        for (int f = 0; f < 4; ++f) {
            #pragma unroll
            for (int kk = 0; kk < 2; ++kk) {
                const short8 kf = *(const short8*)&Ks[f * 16 + t16][kk * 32 + q4 * 8];
                #pragma unroll
                for (int mt = 0; mt < 2; ++mt)
                    s[mt][f] = __builtin_amdgcn_mfma_f32_16x16x32_bf16(
                        qf[mt][kk], kf, s[mt][f], 0, 0, 0);
            }
        }

        // mask for this lane's 4 columns (key = f*16 + t16)
        bool mb[4];
        #pragma unroll
        for (int f = 0; f < 4; ++f) mb[f] = mrow[kt * 64 + f * 16 + t16] != 0;

        // online softmax + P store (bf16, frag-packed columns c = t16*4 + f)
        #pragma unroll
        for (int mt = 0; mt < 2; ++mt) {
            #pragma unroll
            for (int r = 0; r < 4; ++r) {
                float sv[4];
                #pragma unroll
                for (int f = 0; f < 4; ++f)
                    sv[f] = mb[f] ? -3.0e38f : s[mt][f][r] * 0.125f;
                float tm = fmaxf(fmaxf(sv[0], sv[1]), fmaxf(sv[2], sv[3]));
                tm = fmaxf(tm, __shfl_xor(tm, 1));
                tm = fmaxf(tm, __shfl_xor(tm, 2));
                tm = fmaxf(tm, __shfl_xor(tm, 4));
                tm = fmaxf(tm, __shfl_xor(tm, 8));
                const float mold  = m_[mt][r];
                const float mnew  = fmaxf(mold, tm);
                const float alpha = __expf(mold - mnew);
                float e0 = __expf(sv[0] - mnew);
                float e1 = __expf(sv[1] - mnew);
                float e2 = __expf(sv[2] - mnew);
                float e3 = __expf(sv[3] - mnew);
                float rs = (e0 + e1) + (e2 + e3);
                rs += __shfl_xor(rs, 1);
                rs += __shfl_xor(rs, 2);
                rs += __shfl_xor(rs, 4);
                rs += __shfl_xor(rs, 8);
                l_[mt][r] = l_[mt][r] * alpha + rs;
                m_[mt][r] = mnew;
                #pragma unroll
                for (int nt = 0; nt < 4; ++nt) o[mt][nt][r] *= alpha;
                uint2 pk;
                pk.x = (unsigned)f2bf(e0) | ((unsigned)f2bf(e1) << 16);
                pk.y = (unsigned)f2bf(e2) | ((unsigned)f2bf(e3) << 16);
                *(uint2*)&Ps[w][mt * 16 + q4 * 4 + r][t16 * 4] = pk;
            }
        }

        // PV: A-frag = P rows (m = t16, c = kk*32 + q4*8 + j), B-frag = Vt rows
        short8 pf[2][2];
        #pragma unroll
        for (int mt = 0; mt < 2; ++mt)
            #pragma unroll
            for (int kk = 0; kk < 2; ++kk)
                pf[mt][kk] = *(const short8*)&Ps[w][mt * 16 + t16][kk * 32 + q4 * 8];
        #pragma unroll
        for (int nt = 0; nt < 4; ++nt) {
            #pragma unroll
            for (int kk = 0; kk < 2; ++kk) {
                const short8 vf = *(const short8*)&Vts[nt * 16 + t16][kk * 32 + q4 * 8];
                #pragma unroll
                for (int mt = 0; mt < 2; ++mt)
                    o[mt][nt] = __builtin_amdgcn_mfma_f32_16x16x32_bf16(
                        pf[mt][kk], vf, o[mt][nt], 0, 0, 0);
            }
        }
    }

    // epilogue: normalize, write AO (B, N, HID) bf16
    #pragma unroll
    for (int mt = 0; mt < 2; ++mt) {
        #pragma unroll
        for (int r = 0; r < 4; ++r) {
            const int   n   = qrow0 + w * 32 + mt * 16 + q4 * 4 + r;
            const float inv = 1.f / l_[mt][r];
            #pragma unroll
            for (int nt = 0; nt < 4; ++nt)
                AOg[((size_t)(b * N_ + n)) * HID + h * 64 + nt * 16 + t16] =
                    f2bf(o[mt][nt][r] * inv);
        }
    }
}

// ---------------------------------------------------------------------------
extern "C" void kernel_launch(void* const* d_in, const int* in_sizes, int n_in,
                              void* d_out, int out_size, void* d_ws, size_t ws_size,
                              hipStream_t stream) {
    const float* x  = (const float*)d_in[0];
    // d_in[1] = cancer_type (unused: bias_emb/keymod_emb cancel in softmax)
    const unsigned char* mask = (const unsigned char*)d_in[2];
    const float* wq = (const float*)d_in[3];
    const float* bq = (const float*)d_in[4];
    const float* wk = (const float*)d_in[5];
    const float* bk = (const float*)d_in[6];
    const float* wv = (const float*)d_in[7];
    const float* bv = (const float*)d_in[8];
    const float* wo = (const float*)d_in[9];
    const float* bo = (const float*)d_in[10];

    char* ws = (char*)d_ws;
    u16* xb  = (u16*)(ws);
    u16* wqb = (u16*)(ws + (8u << 20));
    u16* wkb = (u16*)(ws + (8u << 20) + (512u << 10));
    u16* wvb = (u16*)(ws + (8u << 20) + (1024u << 10));
    u16* wob = (u16*)(ws + (8u << 20) + (1536u << 10));
    u16* Qg  = (u16*)(ws + (10u << 20));
    u16* Kg  = (u16*)(ws + (18u << 20));
    u16* Vtg = (u16*)(ws + (26u << 20));
    u16* AOg = (u16*)(ws + (34u << 20));

    cvt_x<<<TOK * HID / 1024, 256, 0, stream>>>(x, xb);
    cvt_w<<<dim3(HID * HID / 1024, 4), 256, 0, stream>>>(
        wq, wk, wv, wo, wqb, wkb, wvb, wob);

    gemm_mfma<<<dim3(TOK / 128, HID / 128, 3), 256, 0, stream>>>(
        xb, wqb, wkb, wvb, bq, bk, bv, Qg, Kg, Vtg, 1);

    flash_mfma<<<dim3(N_ / 128, B_ * NH), 256, 0, stream>>>(Qg, Kg, Vtg, mask, AOg);

    gemm_mfma<<<dim3(TOK / 128, HID / 128, 1), 256, 0, stream>>>(
        AOg, wob, wob, wob, bo, bo, bo, d_out, d_out, d_out, 0);
}

// Round 3
// 259.178 us; speedup vs baseline: 3.3373x; 1.1475x over previous
//
#include <hip/hip_runtime.h>

#define B_    4
#define N_    2048
#define HID   512
#define NH    8
#define HD    64
#define TOK   (B_ * N_)   // 8192

typedef __attribute__((ext_vector_type(8))) short short8;
typedef __attribute__((ext_vector_type(4))) float f32x4;
typedef unsigned short u16;

// fp32 -> bf16 round-to-nearest-even
static __device__ __forceinline__ u16 f2bf(float f) {
    unsigned int u = __builtin_bit_cast(unsigned int, f);
    u += 0x7FFFu + ((u >> 16) & 1u);
    return (u16)(u >> 16);
}
// pack two fp32 -> bf16x2 (RNE)
static __device__ __forceinline__ unsigned pkbf(float a, float b) {
    unsigned ua = __builtin_bit_cast(unsigned, a);
    unsigned ub = __builtin_bit_cast(unsigned, b);
    ua += 0x7FFFu + ((ua >> 16) & 1u);
    ub += 0x7FFFu + ((ub >> 16) & 1u);
    return (ua >> 16) | (ub & 0xFFFF0000u);
}

// ---------------------------------------------------------------------------
// fp32 -> bf16 converters
// ---------------------------------------------------------------------------
__global__ __launch_bounds__(256) void cvt_x(const float* __restrict__ src,
                                             u16* __restrict__ dst) {
    const int i = (blockIdx.x * 256 + threadIdx.x) * 4;
    const float4 v = *(const float4*)&src[i];
    ushort4 o;
    o.x = f2bf(v.x); o.y = f2bf(v.y); o.z = f2bf(v.z); o.w = f2bf(v.w);
    *(ushort4*)&dst[i] = o;
}

__global__ __launch_bounds__(256) void cvt_w(
    const float* __restrict__ w0, const float* __restrict__ w1,
    const float* __restrict__ w2, const float* __restrict__ w3,
    u16* __restrict__ d0, u16* __restrict__ d1,
    u16* __restrict__ d2, u16* __restrict__ d3) {
    const float* s = blockIdx.y == 0 ? w0 : blockIdx.y == 1 ? w1 : blockIdx.y == 2 ? w2 : w3;
    u16*        d  = blockIdx.y == 0 ? d0 : blockIdx.y == 1 ? d1 : blockIdx.y == 2 ? d2 : d3;
    const int i = (blockIdx.x * 256 + threadIdx.x) * 4;
    const float4 v = *(const float4*)&s[i];
    ushort4 o;
    o.x = f2bf(v.x); o.y = f2bf(v.y); o.z = f2bf(v.z); o.w = f2bf(v.w);
    *(ushort4*)&d[i] = o;
}

// ---------------------------------------------------------------------------
// bf16 MFMA GEMM (NT): C[i][j] = sum_k A[i][k]*W[j][k] + bias[j]
// 128x128 tile, BK=32, 4 waves 2x2, 4x4 frags of 16x16x32 each.
// qkv=1: write (B,NH,N,HD) bf16; z==0 (Q) additionally scaled by 1/8.
// qkv=0: fp32 flat [TOK][HID].
// ---------------------------------------------------------------------------
__global__ __launch_bounds__(256) void gemm_mfma(
    const u16* __restrict__ A,
    const u16* __restrict__ W0, const u16* __restrict__ W1, const u16* __restrict__ W2,
    const float* __restrict__ bias0, const float* __restrict__ bias1, const float* __restrict__ bias2,
    void* __restrict__ C0, void* __restrict__ C1, void* __restrict__ C2,
    int qkv)
{
    const int z = blockIdx.z;
    const u16*   W    = z == 0 ? W0 : z == 1 ? W1 : W2;
    const float* bias = z == 0 ? bias0 : z == 1 ? bias1 : bias2;

    __shared__ u16 As[128][32];
    __shared__ u16 Bs[128][32];

    const int tid  = threadIdx.x;
    const int row0 = blockIdx.x * 128, col0 = blockIdx.y * 128;
    const int w    = tid >> 6, lane = tid & 63;
    const int wr   = w >> 1, wc = w & 1;
    const int t16  = lane & 15, q4 = lane >> 4;

    const int sm = tid >> 2, sc = (tid & 3) * 8;

    f32x4 acc[4][4];
    #pragma unroll
    for (int mt = 0; mt < 4; ++mt)
        #pragma unroll
        for (int nt = 0; nt < 4; ++nt)
            acc[mt][nt] = (f32x4){0.f, 0.f, 0.f, 0.f};

    for (int k0 = 0; k0 < HID; k0 += 32) {
        __syncthreads();
        #pragma unroll
        for (int p = 0; p < 2; ++p) {
            const int m = sm + 64 * p;
            *(short8*)&As[m][sc] = *(const short8*)&A[(size_t)(row0 + m) * HID + k0 + sc];
            *(short8*)&Bs[m][sc] = *(const short8*)&W[(size_t)(col0 + m) * HID + k0 + sc];
        }
        __syncthreads();

        short8 af[4], bf[4];
        #pragma unroll
        for (int mt = 0; mt < 4; ++mt)
            af[mt] = *(const short8*)&As[wr * 64 + mt * 16 + t16][q4 * 8];
        #pragma unroll
        for (int nt = 0; nt < 4; ++nt)
            bf[nt] = *(const short8*)&Bs[wc * 64 + nt * 16 + t16][q4 * 8];
        #pragma unroll
        for (int mt = 0; mt < 4; ++mt)
            #pragma unroll
            for (int nt = 0; nt < 4; ++nt)
                acc[mt][nt] = __builtin_amdgcn_mfma_f32_16x16x32_bf16(
                    af[mt], bf[nt], acc[mt][nt], 0, 0, 0);
    }

    const float qscale = (qkv && z == 0) ? 0.125f : 1.0f;
    #pragma unroll
    for (int nt = 0; nt < 4; ++nt) {
        const int j  = col0 + wc * 64 + nt * 16 + t16;
        const float bv = bias[j];
        const int h = j >> 6, d = j & 63;
        #pragma unroll
        for (int mt = 0; mt < 4; ++mt) {
            #pragma unroll
            for (int r = 0; r < 4; ++r) {
                const int   i   = row0 + wr * 64 + mt * 16 + q4 * 4 + r;
                const float val = (acc[mt][nt][r] + bv) * qscale;
                if (!qkv) {
                    ((float*)C0)[(size_t)i * HID + j] = val;
                } else {
                    u16* C = (u16*)(z == 0 ? C0 : z == 1 ? C1 : C2);
                    const int b = i >> 11, n = i & (N_ - 1);
                    C[(((size_t)(b * NH + h)) * N_ + n) * HD + d] = f2bf(val);
                }
            }
        }
    }
}

// ---------------------------------------------------------------------------
// V (B,NH,N,HD) -> frag-packed V^T (B,NH,HD,N') with n' = base + (n%16)*4 + (n%64)/16
// (the column order matching the P fragment packing in flash). LDS-tiled so
// both global read and write are coalesced; the scatter stays inside LDS.
// ---------------------------------------------------------------------------
__global__ __launch_bounds__(256) void vtrans(const u16* __restrict__ Vn,
                                              u16* __restrict__ Vt) {
    __shared__ u16 Vs[64][72];
    const int tid = threadIdx.x;
    const size_t hb = (size_t)blockIdx.y * N_ * HD;
    const int n0 = blockIdx.x * 64;

    const int nl = tid >> 2, dc = (tid & 3) * 16;
    *(short8*)&Vs[nl][dc]     = *(const short8*)&Vn[hb + (size_t)(n0 + nl) * HD + dc];
    *(short8*)&Vs[nl][dc + 8] = *(const short8*)&Vn[hb + (size_t)(n0 + nl) * HD + dc + 8];
    __syncthreads();

    const int d = tid >> 2, c0 = (tid & 3) * 16;
    u16 v[16];
    #pragma unroll
    for (int i = 0; i < 16; ++i) {
        const int c = c0 + i;
        const int n = (c & 3) * 16 + (c >> 2);
        v[i] = Vs[n][d];
    }
    u16* dst = &Vt[hb + (size_t)d * N_ + n0 + c0];
    *(short8*)(dst)     = *(const short8*)&v[0];
    *(short8*)(dst + 8) = *(const short8*)&v[8];
}

// ---------------------------------------------------------------------------
// MFMA flash attention, fixed-max softmax (scores are bounded; max-shift is a
// constant along the key axis and cancels, so exp(s) directly is safe in fp32).
// Block = 128 threads (2 waves), 64 Q-rows (32 per wave). Grid (32, 32).
// Row-sum: per-lane partials across all tiles, ONE cross-lane reduce at end.
// Per-head cancer bias / keymod cancel in softmax (constant along key axis).
// ---------------------------------------------------------------------------
__global__ __launch_bounds__(128) void flash_mfma(
    const u16* __restrict__ Qg, const u16* __restrict__ Kg,
    const u16* __restrict__ Vtg, const unsigned char* __restrict__ msk,
    u16* __restrict__ AOg)
{
    __shared__ u16 Ks[64][72];     // [key][d]
    __shared__ u16 Vts[64][72];    // [d][c]  (frag-packed key order)
    __shared__ u16 Ps[2][32][72];  // per-wave P strip [row][c]

    const int tid = threadIdx.x;
    const int w = tid >> 6, lane = tid & 63;
    const int t16 = lane & 15, q4 = lane >> 4;
    const int bh = blockIdx.y, b = bh >> 3, h = bh & 7;
    const int qrow0 = blockIdx.x * 64;

    const size_t hb = (size_t)bh * N_ * HD;
    const u16* Qh  = Qg + hb;
    const u16* Kh  = Kg + hb;
    const u16* Vth = Vtg + hb;
    const unsigned char* mrow = msk + b * N_;

    // Q fragments (A-layout: m = t16, k = q4*8 + j); Q pre-scaled by 1/8
    short8 qf[2][2];
    #pragma unroll
    for (int mt = 0; mt < 2; ++mt)
        #pragma unroll
        for (int kk = 0; kk < 2; ++kk)
            qf[mt][kk] = *(const short8*)
                &Qh[(size_t)(qrow0 + w * 32 + mt * 16 + t16) * HD + kk * 32 + q4 * 8];

    f32x4 o[2][4];
    float lsum[2][4];
    #pragma unroll
    for (int mt = 0; mt < 2; ++mt) {
        #pragma unroll
        for (int nt = 0; nt < 4; ++nt) o[mt][nt] = (f32x4){0.f, 0.f, 0.f, 0.f};
        #pragma unroll
        for (int r = 0; r < 4; ++r) lsum[mt][r] = 0.f;
    }

    const int sr = tid >> 1, scc = (tid & 1) * 32;  // staging: row, col-chunk

    for (int kt = 0; kt < N_ / 64; ++kt) {
        const int kb = kt * 64;
        __syncthreads();
        #pragma unroll
        for (int i = 0; i < 4; ++i) {
            *(short8*)&Ks[sr][scc + i * 8] =
                *(const short8*)&Kh[(size_t)(kb + sr) * HD + scc + i * 8];
            *(short8*)&Vts[sr][scc + i * 8] =
                *(const short8*)&Vth[(size_t)sr * N_ + kb + scc + i * 8];
        }
        __syncthreads();

        // S = Q K^T (already scaled by 1/8 via Q)
        f32x4 s[2][4];
        #pragma unroll
        for (int mt = 0; mt < 2; ++mt)
            #pragma unroll
            for (int f = 0; f < 4; ++f)
                s[mt][f] = (f32x4){0.f, 0.f, 0.f, 0.f};
        #pragma unroll
        for (int f = 0; f < 4; ++f) {
            #pragma unroll
            for (int kk = 0; kk < 2; ++kk) {
                const short8 kf = *(const short8*)&Ks[f * 16 + t16][kk * 32 + q4 * 8];
                #pragma unroll
                for (int mt = 0; mt < 2; ++mt)
                    s[mt][f] = __builtin_amdgcn_mfma_f32_16x16x32_bf16(
                        qf[mt][kk], kf, s[mt][f], 0, 0, 0);
            }
        }

        // additive mask bias for this lane's 4 columns (key = f*16 + t16)
        float mb4[4];
        #pragma unroll
        for (int f = 0; f < 4; ++f)
            mb4[f] = mrow[kb + f * 16 + t16] ? -3.0e38f : 0.f;

        // exp + partial row-sum + bf16 P store (no max tracking, no rescale)
        #pragma unroll
        for (int mt = 0; mt < 2; ++mt) {
            #pragma unroll
            for (int r = 0; r < 4; ++r) {
                const float e0 = __expf(s[mt][0][r] + mb4[0]);
                const float e1 = __expf(s[mt][1][r] + mb4[1]);
                const float e2 = __expf(s[mt][2][r] + mb4[2]);
                const float e3 = __expf(s[mt][3][r] + mb4[3]);
                lsum[mt][r] += (e0 + e1) + (e2 + e3);
                uint2 pk;
                pk.x = pkbf(e0, e1);
                pk.y = pkbf(e2, e3);
                *(uint2*)&Ps[w][mt * 16 + q4 * 4 + r][t16 * 4] = pk;
            }
        }

        // O += P V
        short8 pf[2][2];
        #pragma unroll
        for (int mt = 0; mt < 2; ++mt)
            #pragma unroll
            for (int kk = 0; kk < 2; ++kk)
                pf[mt][kk] = *(const short8*)&Ps[w][mt * 16 + t16][kk * 32 + q4 * 8];
        #pragma unroll
        for (int nt = 0; nt < 4; ++nt) {
            #pragma unroll
            for (int kk = 0; kk < 2; ++kk) {
                const short8 vf = *(const short8*)&Vts[nt * 16 + t16][kk * 32 + q4 * 8];
                #pragma unroll
                for (int mt = 0; mt < 2; ++mt)
                    o[mt][nt] = __builtin_amdgcn_mfma_f32_16x16x32_bf16(
                        pf[mt][kk], vf, o[mt][nt], 0, 0, 0);
            }
        }
    }

    // one cross-lane row-sum reduce (over the t16 dimension), then normalize
    #pragma unroll
    for (int mt = 0; mt < 2; ++mt) {
        #pragma unroll
        for (int r = 0; r < 4; ++r) {
            float l = lsum[mt][r];
            l += __shfl_xor(l, 1);
            l += __shfl_xor(l, 2);
            l += __shfl_xor(l, 4);
            l += __shfl_xor(l, 8);
            const float inv = 1.f / l;
            const int n = qrow0 + w * 32 + mt * 16 + q4 * 4 + r;
            #pragma unroll
            for (int nt = 0; nt < 4; ++nt)
                AOg[((size_t)(b * N_ + n)) * HID + h * 64 + nt * 16 + t16] =
                    f2bf(o[mt][nt][r] * inv);
        }
    }
}

// ---------------------------------------------------------------------------
extern "C" void kernel_launch(void* const* d_in, const int* in_sizes, int n_in,
                              void* d_out, int out_size, void* d_ws, size_t ws_size,
                              hipStream_t stream) {
    const float* x  = (const float*)d_in[0];
    // d_in[1] = cancer_type (unused: bias_emb/keymod_emb cancel in softmax)
    const unsigned char* mask = (const unsigned char*)d_in[2];
    const float* wq = (const float*)d_in[3];
    const float* bq = (const float*)d_in[4];
    const float* wk = (const float*)d_in[5];
    const float* bk = (const float*)d_in[6];
    const float* wv = (const float*)d_in[7];
    const float* bv = (const float*)d_in[8];
    const float* wo = (const float*)d_in[9];
    const float* bo = (const float*)d_in[10];

    char* ws = (char*)d_ws;
    u16* xb  = (u16*)(ws);                      // 8 MB; reused as AOg after QKV gemm
    u16* wqb = (u16*)(ws + (8u << 20));
    u16* wkb = (u16*)(ws + (8u << 20) + (512u << 10));
    u16* wvb = (u16*)(ws + (8u << 20) + (1024u << 10));
    u16* wob = (u16*)(ws + (8u << 20) + (1536u << 10));
    u16* Qg  = (u16*)(ws + (10u << 20));
    u16* Kg  = (u16*)(ws + (18u << 20));
    u16* Vn  = (u16*)(ws + (26u << 20));
    u16* Vtg = (u16*)(ws + (34u << 20));
    u16* AOg = xb;                              // alias: xb dead after QKV gemm

    cvt_x<<<TOK * HID / 1024, 256, 0, stream>>>(x, xb);
    cvt_w<<<dim3(HID * HID / 1024, 4), 256, 0, stream>>>(
        wq, wk, wv, wo, wqb, wkb, wvb, wob);

    gemm_mfma<<<dim3(TOK / 128, HID / 128, 3), 256, 0, stream>>>(
        xb, wqb, wkb, wvb, bq, bk, bv, Qg, Kg, Vn, 1);

    vtrans<<<dim3(N_ / 64, B_ * NH), 256, 0, stream>>>(Vn, Vtg);

    flash_mfma<<<dim3(N_ / 64, B_ * NH), 128, 0, stream>>>(Qg, Kg, Vtg, mask, AOg);

    gemm_mfma<<<dim3(TOK / 128, HID / 128, 1), 256, 0, stream>>>(
        AOg, wob, wob, wob, bo, bo, bo, d_out, d_out, d_out, 0);
}

// Round 4
// 219.938 us; speedup vs baseline: 3.9328x; 1.1784x over previous
//
#include <hip/hip_runtime.h>

#define B_    4
#define N_    2048
#define HID   512
#define NH    8
#define HD    64
#define TOK   (B_ * N_)   // 8192
#define LOG2E 1.4426950408889634f

typedef __attribute__((ext_vector_type(8))) short short8;
typedef __attribute__((ext_vector_type(4))) float f32x4;
typedef unsigned short u16;

// fp32 -> bf16 round-to-nearest-even
static __device__ __forceinline__ u16 f2bf(float f) {
    unsigned int u = __builtin_bit_cast(unsigned int, f);
    u += 0x7FFFu + ((u >> 16) & 1u);
    return (u16)(u >> 16);
}
// pack two fp32 -> bf16x2 (RNE)
static __device__ __forceinline__ unsigned pkbf(float a, float b) {
    unsigned ua = __builtin_bit_cast(unsigned, a);
    unsigned ub = __builtin_bit_cast(unsigned, b);
    ua += 0x7FFFu + ((ua >> 16) & 1u);
    ub += 0x7FFFu + ((ub >> 16) & 1u);
    return (ua >> 16) | (ub & 0xFFFF0000u);
}

// ---------------------------------------------------------------------------
// fp32 -> bf16 converters
// ---------------------------------------------------------------------------
__global__ __launch_bounds__(256) void cvt_x(const float* __restrict__ src,
                                             u16* __restrict__ dst) {
    const int i = (blockIdx.x * 256 + threadIdx.x) * 4;
    const float4 v = *(const float4*)&src[i];
    ushort4 o;
    o.x = f2bf(v.x); o.y = f2bf(v.y); o.z = f2bf(v.z); o.w = f2bf(v.w);
    *(ushort4*)&dst[i] = o;
}

__global__ __launch_bounds__(256) void cvt_w(
    const float* __restrict__ w0, const float* __restrict__ w1,
    const float* __restrict__ w2, const float* __restrict__ w3,
    u16* __restrict__ d0, u16* __restrict__ d1,
    u16* __restrict__ d2, u16* __restrict__ d3) {
    const float* s = blockIdx.y == 0 ? w0 : blockIdx.y == 1 ? w1 : blockIdx.y == 2 ? w2 : w3;
    u16*        d  = blockIdx.y == 0 ? d0 : blockIdx.y == 1 ? d1 : blockIdx.y == 2 ? d2 : d3;
    const int i = (blockIdx.x * 256 + threadIdx.x) * 4;
    const float4 v = *(const float4*)&s[i];
    ushort4 o;
    o.x = f2bf(v.x); o.y = f2bf(v.y); o.z = f2bf(v.z); o.w = f2bf(v.w);
    *(ushort4*)&d[i] = o;
}

// ---------------------------------------------------------------------------
// bf16 MFMA GEMM (NT), register-prefetch pipelined: global loads for K-step
// t+1 are issued before computing step t, so load latency overlaps compute.
// 128x128 tile, BK=32, 4 waves 2x2. qkv=1: bf16 (B,NH,N,HD); z==0 (Q) scaled
// by log2(e)/8 (softmax uses exp2). qkv=0: fp32 flat [TOK][HID].
// LDS leading dim 40 (not 32): breaks the 4-way bank conflict on staging
// writes (stride 80B -> lanes 16 apart land on different banks).
// ---------------------------------------------------------------------------
__global__ __launch_bounds__(256) void gemm_mfma(
    const u16* __restrict__ A,
    const u16* __restrict__ W0, const u16* __restrict__ W1, const u16* __restrict__ W2,
    const float* __restrict__ bias0, const float* __restrict__ bias1, const float* __restrict__ bias2,
    void* __restrict__ C0, void* __restrict__ C1, void* __restrict__ C2,
    int qkv)
{
    const int z = blockIdx.z;
    const u16*   W    = z == 0 ? W0 : z == 1 ? W1 : W2;
    const float* bias = z == 0 ? bias0 : z == 1 ? bias1 : bias2;

    __shared__ u16 As[128][40];
    __shared__ u16 Bs[128][40];

    const int tid  = threadIdx.x;
    const int row0 = blockIdx.x * 128, col0 = blockIdx.y * 128;
    const int w    = tid >> 6, lane = tid & 63;
    const int wr   = w >> 1, wc = w & 1;
    const int t16  = lane & 15, q4 = lane >> 4;

    const int sm = tid >> 2, sc = (tid & 3) * 8;

    f32x4 acc[4][4];
    #pragma unroll
    for (int mt = 0; mt < 4; ++mt)
        #pragma unroll
        for (int nt = 0; nt < 4; ++nt)
            acc[mt][nt] = (f32x4){0.f, 0.f, 0.f, 0.f};

    short8 apre[2], wpre[2];
    #pragma unroll
    for (int p = 0; p < 2; ++p) {
        const int m = sm + 64 * p;
        apre[p] = *(const short8*)&A[(size_t)(row0 + m) * HID + sc];
        wpre[p] = *(const short8*)&W[(size_t)(col0 + m) * HID + sc];
    }

    for (int k0 = 0; k0 < HID; k0 += 32) {
        __syncthreads();
        #pragma unroll
        for (int p = 0; p < 2; ++p) {
            const int m = sm + 64 * p;
            *(short8*)&As[m][sc] = apre[p];
            *(short8*)&Bs[m][sc] = wpre[p];
        }
        __syncthreads();

        if (k0 + 32 < HID) {
            #pragma unroll
            for (int p = 0; p < 2; ++p) {
                const int m = sm + 64 * p;
                apre[p] = *(const short8*)&A[(size_t)(row0 + m) * HID + k0 + 32 + sc];
                wpre[p] = *(const short8*)&W[(size_t)(col0 + m) * HID + k0 + 32 + sc];
            }
        }

        short8 af[4], bf[4];
        #pragma unroll
        for (int mt = 0; mt < 4; ++mt)
            af[mt] = *(const short8*)&As[wr * 64 + mt * 16 + t16][q4 * 8];
        #pragma unroll
        for (int nt = 0; nt < 4; ++nt)
            bf[nt] = *(const short8*)&Bs[wc * 64 + nt * 16 + t16][q4 * 8];
        #pragma unroll
        for (int mt = 0; mt < 4; ++mt)
            #pragma unroll
            for (int nt = 0; nt < 4; ++nt)
                acc[mt][nt] = __builtin_amdgcn_mfma_f32_16x16x32_bf16(
                    af[mt], bf[nt], acc[mt][nt], 0, 0, 0);
    }

    const float qscale = (qkv && z == 0) ? 0.125f * LOG2E : 1.0f;
    #pragma unroll
    for (int nt = 0; nt < 4; ++nt) {
        const int j  = col0 + wc * 64 + nt * 16 + t16;
        const float bv = bias[j];
        const int h = j >> 6, d = j & 63;
        #pragma unroll
        for (int mt = 0; mt < 4; ++mt) {
            #pragma unroll
            for (int r = 0; r < 4; ++r) {
                const int   i   = row0 + wr * 64 + mt * 16 + q4 * 4 + r;
                const float val = (acc[mt][nt][r] + bv) * qscale;
                if (!qkv) {
                    ((float*)C0)[(size_t)i * HID + j] = val;
                } else {
                    u16* C = (u16*)(z == 0 ? C0 : z == 1 ? C1 : C2);
                    const int b = i >> 11, n = i & (N_ - 1);
                    C[(((size_t)(b * NH + h)) * N_ + n) * HD + d] = f2bf(val);
                }
            }
        }
    }
}

// ---------------------------------------------------------------------------
// V (B,NH,N,HD) -> frag-packed V^T (B,NH,HD,N'), n' = base + (n%16)*4 + (n%64)/16.
// ---------------------------------------------------------------------------
__global__ __launch_bounds__(256) void vtrans(const u16* __restrict__ Vn,
                                              u16* __restrict__ Vt) {
    __shared__ u16 Vs[64][72];
    const int tid = threadIdx.x;
    const size_t hb = (size_t)blockIdx.y * N_ * HD;
    const int n0 = blockIdx.x * 64;

    const int nl = tid >> 2, dc = (tid & 3) * 16;
    *(short8*)&Vs[nl][dc]     = *(const short8*)&Vn[hb + (size_t)(n0 + nl) * HD + dc];
    *(short8*)&Vs[nl][dc + 8] = *(const short8*)&Vn[hb + (size_t)(n0 + nl) * HD + dc + 8];
    __syncthreads();

    const int d = tid >> 2, c0 = (tid & 3) * 16;
    u16 v[16];
    #pragma unroll
    for (int i = 0; i < 16; ++i) {
        const int c = c0 + i;
        const int n = (c & 3) * 16 + (c >> 2);
        v[i] = Vs[n][d];
    }
    u16* dst = &Vt[hb + (size_t)d * N_ + n0 + c0];
    *(short8*)(dst)     = *(const short8*)&v[0];
    *(short8*)(dst + 8) = *(const short8*)&v[8];
}

// ---------------------------------------------------------------------------
// MFMA flash attention, fixed-max softmax (scores bounded), exp2-based
// (log2e folded into Q pre-scale). Register-prefetch pipelined K/V staging.
// Block = 128 threads (2 waves), 64 Q-rows. Mask staged once as fp32 bias.
// ---------------------------------------------------------------------------
__global__ __launch_bounds__(128) void flash_mfma(
    const u16* __restrict__ Qg, const u16* __restrict__ Kg,
    const u16* __restrict__ Vtg, const unsigned char* __restrict__ msk,
    u16* __restrict__ AOg)
{
    __shared__ u16 Ks[64][72];     // [key][d]
    __shared__ u16 Vts[64][72];    // [d][c]  (frag-packed key order)
    __shared__ u16 Ps[2][32][72];  // per-wave P strip [row][c]
    __shared__ float Msf[N_];      // additive mask bias

    const int tid = threadIdx.x;
    const int w = tid >> 6, lane = tid & 63;
    const int t16 = lane & 15, q4 = lane >> 4;
    const int bh = blockIdx.y, b = bh >> 3, h = bh & 7;
    const int qrow0 = blockIdx.x * 64;

    const size_t hb = (size_t)bh * N_ * HD;
    const u16* Qh  = Qg + hb;
    const u16* Kh  = Kg + hb;
    const u16* Vth = Vtg + hb;
    const unsigned char* mrow = msk + b * N_;

    // one-time: mask -> fp32 additive bias in LDS
    {
        const uint4 mv = *(const uint4*)&mrow[tid * 16];
        const unsigned wds[4] = {mv.x, mv.y, mv.z, mv.w};
        #pragma unroll
        for (int wd = 0; wd < 4; ++wd)
            #pragma unroll
            for (int by = 0; by < 4; ++by)
                Msf[tid * 16 + wd * 4 + by] =
                    ((wds[wd] >> (8 * by)) & 0xFFu) ? -3.0e38f : 0.f;
    }

    // Q fragments (A-layout: m = t16, k = q4*8 + j); Q pre-scaled by log2e/8
    short8 qf[2][2];
    #pragma unroll
    for (int mt = 0; mt < 2; ++mt)
        #pragma unroll
        for (int kk = 0; kk < 2; ++kk)
            qf[mt][kk] = *(const short8*)
                &Qh[(size_t)(qrow0 + w * 32 + mt * 16 + t16) * HD + kk * 32 + q4 * 8];

    f32x4 o[2][4];
    float lsum[2][4];
    #pragma unroll
    for (int mt = 0; mt < 2; ++mt) {
        #pragma unroll
        for (int nt = 0; nt < 4; ++nt) o[mt][nt] = (f32x4){0.f, 0.f, 0.f, 0.f};
        #pragma unroll
        for (int r = 0; r < 4; ++r) lsum[mt][r] = 0.f;
    }

    const int sr = tid >> 1, scc = (tid & 1) * 32;  // staging: row, col-chunk

    // prefetch tile 0
    short8 kreg[4], vreg[4];
    #pragma unroll
    for (int i = 0; i < 4; ++i) {
        kreg[i] = *(const short8*)&Kh[(size_t)sr * HD + scc + i * 8];
        vreg[i] = *(const short8*)&Vth[(size_t)sr * N_ + scc + i * 8];
    }

    for (int kt = 0; kt < N_ / 64; ++kt) {
        const int kb = kt * 64;
        __syncthreads();                 // prior tile's LDS reads complete
        #pragma unroll
        for (int i = 0; i < 4; ++i) {
            *(short8*)&Ks[sr][scc + i * 8]  = kreg[i];
            *(short8*)&Vts[sr][scc + i * 8] = vreg[i];
        }
        __syncthreads();

        // issue next tile's global loads (latency hidden under compute below)
        if (kt + 1 < N_ / 64) {
            const int kb2 = kb + 64;
            #pragma unroll
            for (int i = 0; i < 4; ++i) {
                kreg[i] = *(const short8*)&Kh[(size_t)(kb2 + sr) * HD + scc + i * 8];
                vreg[i] = *(const short8*)&Vth[(size_t)sr * N_ + kb2 + scc + i * 8];
            }
        }

        // S = Q K^T (includes 1/8 and log2e via Q pre-scale)
        f32x4 s[2][4];
        #pragma unroll
        for (int mt = 0; mt < 2; ++mt)
            #pragma unroll
            for (int f = 0; f < 4; ++f)
                s[mt][f] = (f32x4){0.f, 0.f, 0.f, 0.f};
        #pragma unroll
        for (int f = 0; f < 4; ++f) {
            #pragma unroll
            for (int kk = 0; kk < 2; ++kk) {
                const short8 kf = *(const short8*)&Ks[f * 16 + t16][kk * 32 + q4 * 8];
                #pragma unroll
                for (int mt = 0; mt < 2; ++mt)
                    s[mt][f] = __builtin_amdgcn_mfma_f32_16x16x32_bf16(
                        qf[mt][kk], kf, s[mt][f], 0, 0, 0);
            }
        }

        // additive mask bias for this lane's 4 columns (key = f*16 + t16)
        float mb4[4];
        #pragma unroll
        for (int f = 0; f < 4; ++f) mb4[f] = Msf[kb + f * 16 + t16];

        // exp2 + partial row-sum + bf16 P store
        #pragma unroll
        for (int mt = 0; mt < 2; ++mt) {
            #pragma unroll
            for (int r = 0; r < 4; ++r) {
                const float e0 = exp2f(s[mt][0][r] + mb4[0]);
                const float e1 = exp2f(s[mt][1][r] + mb4[1]);
                const float e2 = exp2f(s[mt][2][r] + mb4[2]);
                const float e3 = exp2f(s[mt][3][r] + mb4[3]);
                lsum[mt][r] += (e0 + e1) + (e2 + e3);
                uint2 pk;
                pk.x = pkbf(e0, e1);
                pk.y = pkbf(e2, e3);
                *(uint2*)&Ps[w][mt * 16 + q4 * 4 + r][t16 * 4] = pk;
            }
        }

        // O += P V
        short8 pf[2][2];
        #pragma unroll
        for (int mt = 0; mt < 2; ++mt)
            #pragma unroll
            for (int kk = 0; kk < 2; ++kk)
                pf[mt][kk] = *(const short8*)&Ps[w][mt * 16 + t16][kk * 32 + q4 * 8];
        #pragma unroll
        for (int nt = 0; nt < 4; ++nt) {
            #pragma unroll
            for (int kk = 0; kk < 2; ++kk) {
                const short8 vf = *(const short8*)&Vts[nt * 16 + t16][kk * 32 + q4 * 8];
                #pragma unroll
                for (int mt = 0; mt < 2; ++mt)
                    o[mt][nt] = __builtin_amdgcn_mfma_f32_16x16x32_bf16(
                        pf[mt][kk], vf, o[mt][nt], 0, 0, 0);
            }
        }
    }

    // one cross-lane row-sum reduce, then normalize + write AO (B,N,HID) bf16
    #pragma unroll
    for (int mt = 0; mt < 2; ++mt) {
        #pragma unroll
        for (int r = 0; r < 4; ++r) {
            float l = lsum[mt][r];
            l += __shfl_xor(l, 1);
            l += __shfl_xor(l, 2);
            l += __shfl_xor(l, 4);
            l += __shfl_xor(l, 8);
            const float inv = 1.f / l;
            const int n = qrow0 + w * 32 + mt * 16 + q4 * 4 + r;
            #pragma unroll
            for (int nt = 0; nt < 4; ++nt)
                AOg[((size_t)(b * N_ + n)) * HID + h * 64 + nt * 16 + t16] =
                    f2bf(o[mt][nt][r] * inv);
        }
    }
}

// ---------------------------------------------------------------------------
extern "C" void kernel_launch(void* const* d_in, const int* in_sizes, int n_in,
                              void* d_out, int out_size, void* d_ws, size_t ws_size,
                              hipStream_t stream) {
    const float* x  = (const float*)d_in[0];
    // d_in[1] = cancer_type (unused: bias_emb/keymod_emb cancel in softmax)
    const unsigned char* mask = (const unsigned char*)d_in[2];
    const float* wq = (const float*)d_in[3];
    const float* bq = (const float*)d_in[4];
    const float* wk = (const float*)d_in[5];
    const float* bk = (const float*)d_in[6];
    const float* wv = (const float*)d_in[7];
    const float* bv = (const float*)d_in[8];
    const float* wo = (const float*)d_in[9];
    const float* bo = (const float*)d_in[10];

    char* ws = (char*)d_ws;
    u16* xb  = (u16*)(ws);                      // 8 MB; reused as AOg after QKV gemm
    u16* wqb = (u16*)(ws + (8u << 20));
    u16* wkb = (u16*)(ws + (8u << 20) + (512u << 10));
    u16* wvb = (u16*)(ws + (8u << 20) + (1024u << 10));
    u16* wob = (u16*)(ws + (8u << 20) + (1536u << 10));
    u16* Qg  = (u16*)(ws + (10u << 20));
    u16* Kg  = (u16*)(ws + (18u << 20));
    u16* Vn  = (u16*)(ws + (26u << 20));
    u16* Vtg = (u16*)(ws + (34u << 20));
    u16* AOg = xb;                              // alias: xb dead after QKV gemm

    cvt_x<<<TOK * HID / 1024, 256, 0, stream>>>(x, xb);
    cvt_w<<<dim3(HID * HID / 1024, 4), 256, 0, stream>>>(
        wq, wk, wv, wo, wqb, wkb, wvb, wob);

    gemm_mfma<<<dim3(TOK / 128, HID / 128, 3), 256, 0, stream>>>(
        xb, wqb, wkb, wvb, bq, bk, bv, Qg, Kg, Vn, 1);

    vtrans<<<dim3(N_ / 64, B_ * NH), 256, 0, stream>>>(Vn, Vtg);

    flash_mfma<<<dim3(N_ / 64, B_ * NH), 128, 0, stream>>>(Qg, Kg, Vtg, mask, AOg);

    gemm_mfma<<<dim3(TOK / 128, HID / 128, 1), 256, 0, stream>>>(
        AOg, wob, wob, wob, bo, bo, bo, d_out, d_out, d_out, 0);
}

// Round 5
// 195.104 us; speedup vs baseline: 4.4333x; 1.1273x over previous
//
#include <hip/hip_runtime.h>

#define B_    4
#define N_    2048
#define HID   512
#define NH    8
#define HD    64
#define TOK   (B_ * N_)   // 8192
#define LOG2E 1.4426950408889634f

typedef __attribute__((ext_vector_type(8))) short short8;
typedef __attribute__((ext_vector_type(4))) float f32x4;
typedef unsigned short u16;

// fp32 -> bf16 round-to-nearest-even
static __device__ __forceinline__ u16 f2bf(float f) {
    unsigned int u = __builtin_bit_cast(unsigned int, f);
    u += 0x7FFFu + ((u >> 16) & 1u);
    return (u16)(u >> 16);
}
// pack two fp32 -> bf16x2 by TRUNCATION: one v_perm_b32.
// low16 = hi16(a), high16 = hi16(b).
static __device__ __forceinline__ unsigned pktrunc(float a, float b) {
    return __builtin_amdgcn_perm(__builtin_bit_cast(unsigned, b),
                                 __builtin_bit_cast(unsigned, a), 0x07060302u);
}

// ---------------------------------------------------------------------------
// One-launch fp32 -> bf16 convert for x + 4 weights.
// blocks 0..4095: x (4.19M elems). blocks 4096..5119: weights (4 x 256 blocks).
// ---------------------------------------------------------------------------
__global__ __launch_bounds__(256) void cvt_all(
    const float* __restrict__ x,
    const float* __restrict__ w0, const float* __restrict__ w1,
    const float* __restrict__ w2, const float* __restrict__ w3,
    u16* __restrict__ xb,
    u16* __restrict__ d0, u16* __restrict__ d1,
    u16* __restrict__ d2, u16* __restrict__ d3)
{
    const int bid = blockIdx.x;
    const float* s;
    u16* d;
    int off;
    if (bid < 4096) { s = x; d = xb; off = bid; }
    else {
        const int t = (bid - 4096) >> 8;
        off = (bid - 4096) & 255;
        s = t == 0 ? w0 : t == 1 ? w1 : t == 2 ? w2 : w3;
        d = t == 0 ? d0 : t == 1 ? d1 : t == 2 ? d2 : d3;
    }
    const int i = off * 1024 + threadIdx.x * 4;
    const float4 v = *(const float4*)&s[i];
    ushort4 o;
    o.x = f2bf(v.x); o.y = f2bf(v.y); o.z = f2bf(v.z); o.w = f2bf(v.w);
    *(ushort4*)&d[i] = o;
}

// ---------------------------------------------------------------------------
// bf16 MFMA GEMM (NT), register-prefetch pipelined. 128x128 tile, BK=32,
// 4 waves 2x2. qkv=1: z0 -> Q (B,NH,N,HD) scaled by log2e/8; z1 -> K same
// layout; z2 -> V written DIRECTLY as frag-packed V^T (B,NH,HD,N') via an
// LDS transpose epilogue (n' = 64*(n/64) + (n%16)*4 + (n%64)/16), coalesced
// 16B stores. qkv=0: fp32 flat [TOK][HID].
// ---------------------------------------------------------------------------
__global__ __launch_bounds__(256) void gemm_mfma(
    const u16* __restrict__ A,
    const u16* __restrict__ W0, const u16* __restrict__ W1, const u16* __restrict__ W2,
    const float* __restrict__ bias0, const float* __restrict__ bias1, const float* __restrict__ bias2,
    void* __restrict__ C0, void* __restrict__ C1, void* __restrict__ C2,
    int qkv)
{
    const int z = blockIdx.z;
    const u16*   W    = z == 0 ? W0 : z == 1 ? W1 : W2;
    const float* bias = z == 0 ? bias0 : z == 1 ? bias1 : bias2;

    __shared__ u16 sh[2 * 128 * 40];             // As | Bs; reused as V strip
    u16 (*As)[40] = (u16(*)[40])sh;
    u16 (*Bs)[40] = (u16(*)[40])(sh + 128 * 40);
    u16 (*St)[72] = (u16(*)[72])sh;              // epilogue V strip [j][n]

    const int tid  = threadIdx.x;
    const int row0 = blockIdx.x * 128, col0 = blockIdx.y * 128;
    const int w    = tid >> 6, lane = tid & 63;
    const int wr   = w >> 1, wc = w & 1;
    const int t16  = lane & 15, q4 = lane >> 4;

    const int sm = tid >> 2, sc = (tid & 3) * 8;

    f32x4 acc[4][4];
    #pragma unroll
    for (int mt = 0; mt < 4; ++mt)
        #pragma unroll
        for (int nt = 0; nt < 4; ++nt)
            acc[mt][nt] = (f32x4){0.f, 0.f, 0.f, 0.f};

    short8 apre[2], wpre[2];
    #pragma unroll
    for (int p = 0; p < 2; ++p) {
        const int m = sm + 64 * p;
        apre[p] = *(const short8*)&A[(size_t)(row0 + m) * HID + sc];
        wpre[p] = *(const short8*)&W[(size_t)(col0 + m) * HID + sc];
    }

    for (int k0 = 0; k0 < HID; k0 += 32) {
        __syncthreads();
        #pragma unroll
        for (int p = 0; p < 2; ++p) {
            const int m = sm + 64 * p;
            *(short8*)&As[m][sc] = apre[p];
            *(short8*)&Bs[m][sc] = wpre[p];
        }
        __syncthreads();

        if (k0 + 32 < HID) {
            #pragma unroll
            for (int p = 0; p < 2; ++p) {
                const int m = sm + 64 * p;
                apre[p] = *(const short8*)&A[(size_t)(row0 + m) * HID + k0 + 32 + sc];
                wpre[p] = *(const short8*)&W[(size_t)(col0 + m) * HID + k0 + 32 + sc];
            }
        }

        short8 af[4], bf[4];
        #pragma unroll
        for (int mt = 0; mt < 4; ++mt)
            af[mt] = *(const short8*)&As[wr * 64 + mt * 16 + t16][q4 * 8];
        #pragma unroll
        for (int nt = 0; nt < 4; ++nt)
            bf[nt] = *(const short8*)&Bs[wc * 64 + nt * 16 + t16][q4 * 8];
        #pragma unroll
        for (int mt = 0; mt < 4; ++mt)
            #pragma unroll
            for (int nt = 0; nt < 4; ++nt)
                acc[mt][nt] = __builtin_amdgcn_mfma_f32_16x16x32_bf16(
                    af[mt], bf[nt], acc[mt][nt], 0, 0, 0);
    }

    if (!qkv) {
        // fp32 flat out
        #pragma unroll
        for (int nt = 0; nt < 4; ++nt) {
            const int j = col0 + wc * 64 + nt * 16 + t16;
            const float bv = bias[j];
            #pragma unroll
            for (int mt = 0; mt < 4; ++mt)
                #pragma unroll
                for (int r = 0; r < 4; ++r) {
                    const int i = row0 + wr * 64 + mt * 16 + q4 * 4 + r;
                    ((float*)C0)[(size_t)i * HID + j] = acc[mt][nt][r] + bv;
                }
        }
    } else if (z < 2) {
        // Q/K: (B,NH,N,HD) bf16, Q scaled by log2e/8
        const float qscale = (z == 0) ? 0.125f * LOG2E : 1.0f;
        u16* C = (u16*)(z == 0 ? C0 : C1);
        #pragma unroll
        for (int nt = 0; nt < 4; ++nt) {
            const int j = col0 + wc * 64 + nt * 16 + t16;
            const float bv = bias[j];
            const int h = j >> 6, d = j & 63;
            #pragma unroll
            for (int mt = 0; mt < 4; ++mt)
                #pragma unroll
                for (int r = 0; r < 4; ++r) {
                    const int i = row0 + wr * 64 + mt * 16 + q4 * 4 + r;
                    const int b = i >> 11, n = i & (N_ - 1);
                    C[(((size_t)(b * NH + h)) * N_ + n) * HD + d] =
                        f2bf((acc[mt][nt][r] + bv) * qscale);
                }
        }
    } else {
        // V: LDS-transpose epilogue -> frag-packed V^T, coalesced stores.
        u16* Vt = (u16*)C2;
        const int b = row0 >> 11;
        #pragma unroll
        for (int p = 0; p < 2; ++p) {
            __syncthreads();                 // main-loop LDS (or pass p-1) dead
            if (wr == p) {
                #pragma unroll
                for (int nt = 0; nt < 4; ++nt) {
                    const int jp = wc * 64 + nt * 16 + t16;
                    const float bv = bias[col0 + jp];
                    #pragma unroll
                    for (int mt = 0; mt < 4; ++mt) {
                        const float v0 = acc[mt][nt][0] + bv;
                        const float v1 = acc[mt][nt][1] + bv;
                        const float v2 = acc[mt][nt][2] + bv;
                        const float v3 = acc[mt][nt][3] + bv;
                        uint2 pk;
                        pk.x = pktrunc(v0, v1);
                        pk.y = pktrunc(v2, v3);
                        *(uint2*)&St[jp][mt * 16 + q4 * 4] = pk;
                    }
                }
            }
            __syncthreads();
            const int nb = (row0 & (N_ - 1)) + p * 64;
            #pragma unroll
            for (int it = 0; it < 2; ++it) {
                const int task = tid + it * 256;      // 0..511
                const int jp = task >> 2, qc = task & 3;
                u16 v[16];
                #pragma unroll
                for (int e = 0; e < 16; ++e) {
                    const int np = qc * 16 + e;               // n' within 64-group
                    const int n  = ((np & 3) << 4) | (np >> 2); // source n
                    v[e] = St[jp][n];
                }
                const int j = col0 + jp, h = j >> 6, d = j & 63;
                u16* dst = &Vt[(((size_t)(b * NH + h)) * HD + d) * N_ + nb + qc * 16];
                *(short8*)(dst)     = *(const short8*)&v[0];
                *(short8*)(dst + 8) = *(const short8*)&v[8];
            }
        }
    }
}

// ---------------------------------------------------------------------------
// MFMA flash attention. Fixed-max softmax (scores bounded; per-row shift
// cancels), raw v_exp_f32 via __builtin_amdgcn_exp2f (log2e folded into Q).
// Mask applied as bitwise AND on packed bf16 P (masked => P=0, consistent in
// numerator and denominator). Row-sum computed BY MFMA against an all-ones
// B fragment from the same truncated P (cancels truncation bias, kills all
// lsum VALU + final shuffle reduce). Register-prefetch pipelined staging.
// Block = 128 threads (2 waves), 64 Q-rows.
// ---------------------------------------------------------------------------
__global__ __launch_bounds__(128) void flash_mfma(
    const u16* __restrict__ Qg, const u16* __restrict__ Kg,
    const u16* __restrict__ Vtg, const unsigned char* __restrict__ msk,
    u16* __restrict__ AOg)
{
    __shared__ u16 Ks[64][72];        // [key][d]
    __shared__ u16 Vts[64][72];       // [d][c]  (frag-packed key order)
    __shared__ u16 Ps[2][32][72];     // per-wave P strip [row][c]
    __shared__ unsigned Mnd[N_ / 64][32];  // AND-masks: [kt][t16*2 + word]

    const int tid = threadIdx.x;
    const int w = tid >> 6, lane = tid & 63;
    const int t16 = lane & 15, q4 = lane >> 4;
    const int bh = blockIdx.y, b = bh >> 3, h = bh & 7;
    const int qrow0 = blockIdx.x * 64;

    const size_t hb = (size_t)bh * N_ * HD;
    const u16* Qh  = Qg + hb;
    const u16* Kh  = Kg + hb;
    const u16* Vth = Vtg + hb;
    const unsigned char* mrow = msk + b * N_;

    // build packed AND-mask table: word0 = keys (kb+t16, kb+16+t16),
    // word1 = keys (kb+32+t16, kb+48+t16)
    #pragma unroll
    for (int it = 0; it < 8; ++it) {
        const int e = tid + it * 128;          // 0..1023
        const int kt = e >> 5, sl = e & 31;
        const int tt = sl >> 1, wd = sl & 1;
        const int k0 = kt * 64 + wd * 32 + tt;
        const unsigned lo = mrow[k0]      ? 0u : 0x0000FFFFu;
        const unsigned hi = mrow[k0 + 16] ? 0u : 0xFFFF0000u;
        Mnd[kt][sl] = lo | hi;
    }

    // Q fragments (A-layout: m = t16, k = q4*8 + j); Q pre-scaled by log2e/8
    short8 qf[2][2];
    #pragma unroll
    for (int mt = 0; mt < 2; ++mt)
        #pragma unroll
        for (int kk = 0; kk < 2; ++kk)
            qf[mt][kk] = *(const short8*)
                &Qh[(size_t)(qrow0 + w * 32 + mt * 16 + t16) * HD + kk * 32 + q4 * 8];

    const short8 ones8 = {0x3F80, 0x3F80, 0x3F80, 0x3F80,
                          0x3F80, 0x3F80, 0x3F80, 0x3F80};  // bf16 1.0 x8

    f32x4 o[2][4], ls[2];
    #pragma unroll
    for (int mt = 0; mt < 2; ++mt) {
        #pragma unroll
        for (int nt = 0; nt < 4; ++nt) o[mt][nt] = (f32x4){0.f, 0.f, 0.f, 0.f};
        ls[mt] = (f32x4){0.f, 0.f, 0.f, 0.f};
    }

    const int sr = tid >> 1, scc = (tid & 1) * 32;  // staging: row, col-chunk

    // prefetch tile 0
    short8 kreg[4], vreg[4];
    #pragma unroll
    for (int i = 0; i < 4; ++i) {
        kreg[i] = *(const short8*)&Kh[(size_t)sr * HD + scc + i * 8];
        vreg[i] = *(const short8*)&Vth[(size_t)sr * N_ + scc + i * 8];
    }

    for (int kt = 0; kt < N_ / 64; ++kt) {
        const int kb = kt * 64;
        __syncthreads();                 // prior tile's LDS reads complete
        #pragma unroll
        for (int i = 0; i < 4; ++i) {
            *(short8*)&Ks[sr][scc + i * 8]  = kreg[i];
            *(short8*)&Vts[sr][scc + i * 8] = vreg[i];
        }
        __syncthreads();

        // issue next tile's global loads (latency hidden under compute)
        if (kt + 1 < N_ / 64) {
            const int kb2 = kb + 64;
            #pragma unroll
            for (int i = 0; i < 4; ++i) {
                kreg[i] = *(const short8*)&Kh[(size_t)(kb2 + sr) * HD + scc + i * 8];
                vreg[i] = *(const short8*)&Vth[(size_t)sr * N_ + kb2 + scc + i * 8];
            }
        }

        // S = Q K^T (1/8 and log2e pre-folded into Q)
        f32x4 s[2][4];
        #pragma unroll
        for (int mt = 0; mt < 2; ++mt)
            #pragma unroll
            for (int f = 0; f < 4; ++f)
                s[mt][f] = (f32x4){0.f, 0.f, 0.f, 0.f};
        #pragma unroll
        for (int f = 0; f < 4; ++f) {
            #pragma unroll
            for (int kk = 0; kk < 2; ++kk) {
                const short8 kf = *(const short8*)&Ks[f * 16 + t16][kk * 32 + q4 * 8];
                #pragma unroll
                for (int mt = 0; mt < 2; ++mt)
                    s[mt][f] = __builtin_amdgcn_mfma_f32_16x16x32_bf16(
                        qf[mt][kk], kf, s[mt][f], 0, 0, 0);
            }
        }

        const uint2 mnd = *(const uint2*)&Mnd[kt][t16 * 2];

        // exp2 + truncation-pack + mask-AND + P store (pure: 8 VALU / 4 scores)
        #pragma unroll
        for (int mt = 0; mt < 2; ++mt) {
            #pragma unroll
            for (int r = 0; r < 4; ++r) {
                const float e0 = __builtin_amdgcn_exp2f(s[mt][0][r]);
                const float e1 = __builtin_amdgcn_exp2f(s[mt][1][r]);
                const float e2 = __builtin_amdgcn_exp2f(s[mt][2][r]);
                const float e3 = __builtin_amdgcn_exp2f(s[mt][3][r]);
                uint2 pk;
                pk.x = pktrunc(e0, e1) & mnd.x;
                pk.y = pktrunc(e2, e3) & mnd.y;
                *(uint2*)&Ps[w][mt * 16 + q4 * 4 + r][t16 * 4] = pk;
            }
        }

        // O += P V ; row-sum += P * ones  (same truncated P -> bias cancels)
        short8 pf[2][2];
        #pragma unroll
        for (int mt = 0; mt < 2; ++mt)
            #pragma unroll
            for (int kk = 0; kk < 2; ++kk)
                pf[mt][kk] = *(const short8*)&Ps[w][mt * 16 + t16][kk * 32 + q4 * 8];
        #pragma unroll
        for (int mt = 0; mt < 2; ++mt)
            #pragma unroll
            for (int kk = 0; kk < 2; ++kk)
                ls[mt] = __builtin_amdgcn_mfma_f32_16x16x32_bf16(
                    pf[mt][kk], ones8, ls[mt], 0, 0, 0);
        #pragma unroll
        for (int nt = 0; nt < 4; ++nt) {
            #pragma unroll
            for (int kk = 0; kk < 2; ++kk) {
                const short8 vf = *(const short8*)&Vts[nt * 16 + t16][kk * 32 + q4 * 8];
                #pragma unroll
                for (int mt = 0; mt < 2; ++mt)
                    o[mt][nt] = __builtin_amdgcn_mfma_f32_16x16x32_bf16(
                        pf[mt][kk], vf, o[mt][nt], 0, 0, 0);
            }
        }
    }

    // normalize (row sum already per-lane via ones-MFMA) + write AO bf16
    #pragma unroll
    for (int mt = 0; mt < 2; ++mt) {
        #pragma unroll
        for (int r = 0; r < 4; ++r) {
            const float inv = 1.f / ls[mt][r];
            const int n = qrow0 + w * 32 + mt * 16 + q4 * 4 + r;
            #pragma unroll
            for (int nt = 0; nt < 4; ++nt)
                AOg[((size_t)(b * N_ + n)) * HID + h * 64 + nt * 16 + t16] =
                    f2bf(o[mt][nt][r] * inv);
        }
    }
}

// ---------------------------------------------------------------------------
extern "C" void kernel_launch(void* const* d_in, const int* in_sizes, int n_in,
                              void* d_out, int out_size, void* d_ws, size_t ws_size,
                              hipStream_t stream) {
    const float* x  = (const float*)d_in[0];
    // d_in[1] = cancer_type (unused: bias_emb/keymod_emb cancel in softmax)
    const unsigned char* mask = (const unsigned char*)d_in[2];
    const float* wq = (const float*)d_in[3];
    const float* bq = (const float*)d_in[4];
    const float* wk = (const float*)d_in[5];
    const float* bk = (const float*)d_in[6];
    const float* wv = (const float*)d_in[7];
    const float* bv = (const float*)d_in[8];
    const float* wo = (const float*)d_in[9];
    const float* bo = (const float*)d_in[10];

    char* ws = (char*)d_ws;
    u16* xb  = (u16*)(ws);                      // 8 MB; reused as AOg after QKV gemm
    u16* wqb = (u16*)(ws + (8u << 20));
    u16* wkb = (u16*)(ws + (8u << 20) + (512u << 10));
    u16* wvb = (u16*)(ws + (8u << 20) + (1024u << 10));
    u16* wob = (u16*)(ws + (8u << 20) + (1536u << 10));
    u16* Qg  = (u16*)(ws + (10u << 20));
    u16* Kg  = (u16*)(ws + (18u << 20));
    u16* Vtg = (u16*)(ws + (26u << 20));
    u16* AOg = xb;                              // alias: xb dead after QKV gemm

    cvt_all<<<5120, 256, 0, stream>>>(x, wq, wk, wv, wo, xb, wqb, wkb, wvb, wob);

    gemm_mfma<<<dim3(TOK / 128, HID / 128, 3), 256, 0, stream>>>(
        xb, wqb, wkb, wvb, bq, bk, bv, Qg, Kg, Vtg, 1);

    flash_mfma<<<dim3(N_ / 64, B_ * NH), 128, 0, stream>>>(Qg, Kg, Vtg, mask, AOg);

    gemm_mfma<<<dim3(TOK / 128, HID / 128, 1), 256, 0, stream>>>(
        AOg, wob, wob, wob, bo, bo, bo, d_out, d_out, d_out, 0);
}

// Round 6
// 178.781 us; speedup vs baseline: 4.8381x; 1.0913x over previous
//
#include <hip/hip_runtime.h>

#define B_    4
#define N_    2048
#define HID   512
#define NH    8
#define HD    64
#define TOK   (B_ * N_)   // 8192
#define LOG2E 1.4426950408889634f

typedef __attribute__((ext_vector_type(8))) short short8;
typedef __attribute__((ext_vector_type(4))) float f32x4;
typedef unsigned short u16;

// fp32 -> bf16 round-to-nearest-even
static __device__ __forceinline__ u16 f2bf(float f) {
    unsigned int u = __builtin_bit_cast(unsigned int, f);
    u += 0x7FFFu + ((u >> 16) & 1u);
    return (u16)(u >> 16);
}
// pack two fp32 -> bf16x2 by TRUNCATION: one v_perm_b32.
static __device__ __forceinline__ unsigned pktrunc(float a, float b) {
    return __builtin_amdgcn_perm(__builtin_bit_cast(unsigned, b),
                                 __builtin_bit_cast(unsigned, a), 0x07060302u);
}

// async global->LDS DMA, 16 B/lane. LDS dest = wave-uniform base + lane*16.
// Pointer casts go through integers: global generic==AS1 address; LDS generic
// low 32 bits == AS3 offset.
static __device__ __forceinline__ void dma16(const void* g, void* l) {
    __builtin_amdgcn_global_load_lds(
        (const __attribute__((address_space(1))) unsigned int*)(unsigned long long)g,
        (__attribute__((address_space(3))) unsigned int*)(unsigned int)(unsigned long long)l,
        16, 0, 0);
}

// ---------------------------------------------------------------------------
// One-launch fp32 -> bf16 convert for x + 4 weights.
// ---------------------------------------------------------------------------
__global__ __launch_bounds__(256) void cvt_all(
    const float* __restrict__ x,
    const float* __restrict__ w0, const float* __restrict__ w1,
    const float* __restrict__ w2, const float* __restrict__ w3,
    u16* __restrict__ xb,
    u16* __restrict__ d0, u16* __restrict__ d1,
    u16* __restrict__ d2, u16* __restrict__ d3)
{
    const int bid = blockIdx.x;
    const float* s;
    u16* d;
    int off;
    if (bid < 4096) { s = x; d = xb; off = bid; }
    else {
        const int t = (bid - 4096) >> 8;
        off = (bid - 4096) & 255;
        s = t == 0 ? w0 : t == 1 ? w1 : t == 2 ? w2 : w3;
        d = t == 0 ? d0 : t == 1 ? d1 : t == 2 ? d2 : d3;
    }
    const int i = off * 1024 + threadIdx.x * 4;
    const float4 v = *(const float4*)&s[i];
    ushort4 o;
    o.x = f2bf(v.x); o.y = f2bf(v.y); o.z = f2bf(v.z); o.w = f2bf(v.w);
    *(ushort4*)&d[i] = o;
}

// ---------------------------------------------------------------------------
// bf16 MFMA GEMM (NT), DMA-staged + double-buffered, ONE barrier per K-step.
// 128x128 tile, BK=32, 4 waves 2x2. LDS layout unpadded [128][32] with XOR
// swizzle c8' = c8 ^ ((m ^ (m>>2)) & 3)  (keeps b128 frag reads at 2-way).
// qkv=1: z0 -> Q (B,NH,N,HD) scaled by log2e/8; z1 -> K; z2 -> V written as
// frag-packed V^T (B,NH,HD,N') via LDS transpose epilogue. qkv=0: fp32 flat.
// ---------------------------------------------------------------------------
__global__ __launch_bounds__(256) void gemm_mfma(
    const u16* __restrict__ A,
    const u16* __restrict__ W0, const u16* __restrict__ W1, const u16* __restrict__ W2,
    const float* __restrict__ bias0, const float* __restrict__ bias1, const float* __restrict__ bias2,
    void* __restrict__ C0, void* __restrict__ C1, void* __restrict__ C2,
    int qkv)
{
    const int z = blockIdx.z;
    const u16*   W    = z == 0 ? W0 : z == 1 ? W1 : W2;
    const float* bias = z == 0 ? bias0 : z == 1 ? bias1 : bias2;

    __shared__ u16 ABs[2][2][128 * 32];   // [buf][A/B][m*32 + c8'*8]

    const int tid  = threadIdx.x;
    const int row0 = blockIdx.x * 128, col0 = blockIdx.y * 128;
    const int w    = tid >> 6, lane = tid & 63;
    const int wr   = w >> 1, wc = w & 1;
    const int t16  = lane & 15, q4 = lane >> 4;

    // DMA lane geometry: chunk = 1024B = 16 rows; lane l -> row l>>2,
    // physical 16B slot l&3; logical k-chunk = (l&3)^((l>>2)&3)^((l>>4)&3).
    const int dmr  = lane >> 2;
    const int dmc8 = (lane & 3) ^ ((lane >> 2) & 3) ^ ((lane >> 4) & 3);

    f32x4 acc[4][4];
    #pragma unroll
    for (int mt = 0; mt < 4; ++mt)
        #pragma unroll
        for (int nt = 0; nt < 4; ++nt)
            acc[mt][nt] = (f32x4){0.f, 0.f, 0.f, 0.f};

    // wave w stages chunks {2w, 2w+1} of each of A and B per K-step
    #define GEMM_DMA(p, k0)                                                     \
        _Pragma("unroll")                                                       \
        for (int i = 0; i < 2; ++i) {                                           \
            const int c = w * 2 + i;                                            \
            dma16(&A[(size_t)(row0 + c * 16 + dmr) * HID + (k0) + dmc8 * 8],    \
                  &ABs[p][0][c * 512]);                                         \
            dma16(&W[(size_t)(col0 + c * 16 + dmr) * HID + (k0) + dmc8 * 8],    \
                  &ABs[p][1][c * 512]);                                         \
        }

    GEMM_DMA(0, 0)

    const int swz = (t16 ^ (t16 >> 2)) & 3;

    for (int it = 0; it < HID / 32; ++it) {
        __syncthreads();                       // drains DMA(it); closes buf reads
        if (it + 1 < HID / 32) { GEMM_DMA((it + 1) & 1, (it + 1) * 32) }

        const int p = it & 1;
        short8 af[4], bf[4];
        #pragma unroll
        for (int mt = 0; mt < 4; ++mt)
            af[mt] = *(const short8*)&ABs[p][0][(wr * 64 + mt * 16 + t16) * 32 + (q4 ^ swz) * 8];
        #pragma unroll
        for (int nt = 0; nt < 4; ++nt)
            bf[nt] = *(const short8*)&ABs[p][1][(wc * 64 + nt * 16 + t16) * 32 + (q4 ^ swz) * 8];
        #pragma unroll
        for (int mt = 0; mt < 4; ++mt)
            #pragma unroll
            for (int nt = 0; nt < 4; ++nt)
                acc[mt][nt] = __builtin_amdgcn_mfma_f32_16x16x32_bf16(
                    af[mt], bf[nt], acc[mt][nt], 0, 0, 0);
    }

    if (!qkv) {
        #pragma unroll
        for (int nt = 0; nt < 4; ++nt) {
            const int j = col0 + wc * 64 + nt * 16 + t16;
            const float bv = bias[j];
            #pragma unroll
            for (int mt = 0; mt < 4; ++mt)
                #pragma unroll
                for (int r = 0; r < 4; ++r) {
                    const int i = row0 + wr * 64 + mt * 16 + q4 * 4 + r;
                    ((float*)C0)[(size_t)i * HID + j] = acc[mt][nt][r] + bv;
                }
        }
    } else if (z < 2) {
        const float qscale = (z == 0) ? 0.125f * LOG2E : 1.0f;
        u16* C = (u16*)(z == 0 ? C0 : C1);
        #pragma unroll
        for (int nt = 0; nt < 4; ++nt) {
            const int j = col0 + wc * 64 + nt * 16 + t16;
            const float bv = bias[j];
            const int h = j >> 6, d = j & 63;
            #pragma unroll
            for (int mt = 0; mt < 4; ++mt)
                #pragma unroll
                for (int r = 0; r < 4; ++r) {
                    const int i = row0 + wr * 64 + mt * 16 + q4 * 4 + r;
                    const int b = i >> 11, n = i & (N_ - 1);
                    C[(((size_t)(b * NH + h)) * N_ + n) * HD + d] =
                        f2bf((acc[mt][nt][r] + bv) * qscale);
                }
        }
    } else {
        // V: LDS-transpose epilogue -> frag-packed V^T, coalesced stores.
        u16* Vt = (u16*)C2;
        u16 (*St)[72] = (u16(*)[72])&ABs[0][0][0];   // 128 x 72 = 18.4 KB
        const int b = row0 >> 11;
        #pragma unroll
        for (int p = 0; p < 2; ++p) {
            __syncthreads();
            if (wr == p) {
                #pragma unroll
                for (int nt = 0; nt < 4; ++nt) {
                    const int jp = wc * 64 + nt * 16 + t16;
                    const float bv = bias[col0 + jp];
                    #pragma unroll
                    for (int mt = 0; mt < 4; ++mt) {
                        uint2 pk;
                        pk.x = pktrunc(acc[mt][nt][0] + bv, acc[mt][nt][1] + bv);
                        pk.y = pktrunc(acc[mt][nt][2] + bv, acc[mt][nt][3] + bv);
                        *(uint2*)&St[jp][mt * 16 + q4 * 4] = pk;
                    }
                }
            }
            __syncthreads();
            const int nb = (row0 & (N_ - 1)) + p * 64;
            #pragma unroll
            for (int it = 0; it < 2; ++it) {
                const int task = tid + it * 256;
                const int jp = task >> 2, qc = task & 3;
                u16 v[16];
                #pragma unroll
                for (int e = 0; e < 16; ++e) {
                    const int np = qc * 16 + e;
                    const int n  = ((np & 3) << 4) | (np >> 2);
                    v[e] = St[jp][n];
                }
                const int j = col0 + jp, h = j >> 6, d = j & 63;
                u16* dst = &Vt[(((size_t)(b * NH + h)) * HD + d) * N_ + nb + qc * 16];
                *(short8*)(dst)     = *(const short8*)&v[0];
                *(short8*)(dst + 8) = *(const short8*)&v[8];
            }
        }
    }
}

// ---------------------------------------------------------------------------
// MFMA flash attention. Fixed-max softmax, raw v_exp_f32, mask as bitwise AND
// on packed P, row-sum via ones-MFMA. K/V staged by DMA into double-buffered
// unpadded LDS with XOR swizzle c8' = c8 ^ (row & 7); ONE barrier per K-tile.
// Block = 256 threads (4 waves), 128 Q-rows (32 per wave). Grid (16, 32).
// ---------------------------------------------------------------------------
__global__ __launch_bounds__(256) void flash_mfma(
    const u16* __restrict__ Qg, const u16* __restrict__ Kg,
    const u16* __restrict__ Vtg, const unsigned char* __restrict__ msk,
    u16* __restrict__ AOg)
{
    __shared__ u16 KVs[2][2][64 * 64];    // [buf][K/Vt][row*64 + c8'*8]
    __shared__ u16 Ps[4][32][72];         // per-wave P strip [row][c], padded
    __shared__ unsigned Mnd[N_ / 64][32]; // AND-masks [kt][t16*2 + word]

    const int tid = threadIdx.x;
    const int w = tid >> 6, lane = tid & 63;
    const int t16 = lane & 15, q4 = lane >> 4;
    const int bh = blockIdx.y, b = bh >> 3, h = bh & 7;
    const int qrow0 = blockIdx.x * 128;
    const int qbase = qrow0 + w * 32;

    const size_t hb = (size_t)bh * N_ * HD;
    const u16* Qh  = Qg + hb;
    const u16* Kh  = Kg + hb;
    const u16* Vth = Vtg + hb;
    const unsigned char* mrow = msk + b * N_;

    // packed AND-mask table (1024 entries, 256 threads x 4)
    #pragma unroll
    for (int it = 0; it < 4; ++it) {
        const int e = tid + it * 256;
        const int kt = e >> 5, sl = e & 31;
        const int tt = sl >> 1, wd = sl & 1;
        const int k0 = kt * 64 + wd * 32 + tt;
        const unsigned lo = mrow[k0]      ? 0u : 0x0000FFFFu;
        const unsigned hi = mrow[k0 + 16] ? 0u : 0xFFFF0000u;
        Mnd[kt][sl] = lo | hi;
    }

    // Q fragments (A-layout: m = t16, k = q4*8 + j); Q pre-scaled by log2e/8
    short8 qf[2][2];
    #pragma unroll
    for (int mt = 0; mt < 2; ++mt)
        #pragma unroll
        for (int kk = 0; kk < 2; ++kk)
            qf[mt][kk] = *(const short8*)
                &Qh[(size_t)(qbase + mt * 16 + t16) * HD + kk * 32 + q4 * 8];

    const short8 ones8 = {0x3F80, 0x3F80, 0x3F80, 0x3F80,
                          0x3F80, 0x3F80, 0x3F80, 0x3F80};

    f32x4 o[2][4], ls[2];
    #pragma unroll
    for (int mt = 0; mt < 2; ++mt) {
        #pragma unroll
        for (int nt = 0; nt < 4; ++nt) o[mt][nt] = (f32x4){0.f, 0.f, 0.f, 0.f};
        ls[mt] = (f32x4){0.f, 0.f, 0.f, 0.f};
    }

    // DMA lane geometry: chunk = 1024B = 8 rows of 128B; lane l -> row l>>3,
    // physical slot l&7, logical c8 = (l&7) ^ ((l>>3)&7).
    const int dmr  = lane >> 3;
    const int dmc8 = (lane & 7) ^ ((lane >> 3) & 7);

    // wave w stages K chunks {2w, 2w+1} and Vt chunks {2w, 2w+1}
    #define FLASH_DMA(p, kb)                                                    \
        _Pragma("unroll")                                                       \
        for (int i = 0; i < 2; ++i) {                                           \
            const int c = w * 2 + i;                                            \
            dma16(&Kh[(size_t)((kb) + c * 8 + dmr) * HD + dmc8 * 8],            \
                  &KVs[p][0][c * 512]);                                         \
            dma16(&Vth[(size_t)(c * 8 + dmr) * N_ + (kb) + dmc8 * 8],           \
                  &KVs[p][1][c * 512]);                                         \
        }

    FLASH_DMA(0, 0)

    const int swz7 = t16 & 7;

    for (int kt = 0; kt < N_ / 64; ++kt) {
        __syncthreads();                  // drains DMA(kt); closes old buf reads
        if (kt + 1 < N_ / 64) { FLASH_DMA((kt + 1) & 1, (kt + 1) * 64) }
        const int p = kt & 1;

        // S = Q K^T (1/8 and log2e pre-folded into Q)
        f32x4 s[2][4];
        #pragma unroll
        for (int mt = 0; mt < 2; ++mt)
            #pragma unroll
            for (int f = 0; f < 4; ++f)
                s[mt][f] = (f32x4){0.f, 0.f, 0.f, 0.f};
        #pragma unroll
        for (int f = 0; f < 4; ++f) {
            #pragma unroll
            for (int kk = 0; kk < 2; ++kk) {
                const short8 kf = *(const short8*)
                    &KVs[p][0][(f * 16 + t16) * 64 + ((kk * 4 + q4) ^ swz7) * 8];
                #pragma unroll
                for (int mt = 0; mt < 2; ++mt)
                    s[mt][f] = __builtin_amdgcn_mfma_f32_16x16x32_bf16(
                        qf[mt][kk], kf, s[mt][f], 0, 0, 0);
            }
        }

        const uint2 mnd = *(const uint2*)&Mnd[kt][t16 * 2];

        // exp2 + truncation-pack + mask-AND + P store
        #pragma unroll
        for (int mt = 0; mt < 2; ++mt) {
            #pragma unroll
            for (int r = 0; r < 4; ++r) {
                const float e0 = __builtin_amdgcn_exp2f(s[mt][0][r]);
                const float e1 = __builtin_amdgcn_exp2f(s[mt][1][r]);
                const float e2 = __builtin_amdgcn_exp2f(s[mt][2][r]);
                const float e3 = __builtin_amdgcn_exp2f(s[mt][3][r]);
                uint2 pk;
                pk.x = pktrunc(e0, e1) & mnd.x;
                pk.y = pktrunc(e2, e3) & mnd.y;
                *(uint2*)&Ps[w][mt * 16 + q4 * 4 + r][t16 * 4] = pk;
            }
        }

        // O += P V ; row-sum += P * ones
        short8 pf[2][2];
        #pragma unroll
        for (int mt = 0; mt < 2; ++mt)
            #pragma unroll
            for (int kk = 0; kk < 2; ++kk)
                pf[mt][kk] = *(const short8*)&Ps[w][mt * 16 + t16][kk * 32 + q4 * 8];
        #pragma unroll
        for (int mt = 0; mt < 2; ++mt)
            #pragma unroll
            for (int kk = 0; kk < 2; ++kk)
                ls[mt] = __builtin_amdgcn_mfma_f32_16x16x32_bf16(
                    pf[mt][kk], ones8, ls[mt], 0, 0, 0);
        #pragma unroll
        for (int nt = 0; nt < 4; ++nt) {
            #pragma unroll
            for (int kk = 0; kk < 2; ++kk) {
                const short8 vf = *(const short8*)
                    &KVs[p][1][(nt * 16 + t16) * 64 + ((kk * 4 + q4) ^ swz7) * 8];
                #pragma unroll
                for (int mt = 0; mt < 2; ++mt)
                    o[mt][nt] = __builtin_amdgcn_mfma_f32_16x16x32_bf16(
                        pf[mt][kk], vf, o[mt][nt], 0, 0, 0);
            }
        }
    }

    // normalize + write AO (B,N,HID) bf16
    #pragma unroll
    for (int mt = 0; mt < 2; ++mt) {
        #pragma unroll
        for (int r = 0; r < 4; ++r) {
            const float inv = 1.f / ls[mt][r];
            const int n = qbase + mt * 16 + q4 * 4 + r;
            #pragma unroll
            for (int nt = 0; nt < 4; ++nt)
                AOg[((size_t)(b * N_ + n)) * HID + h * 64 + nt * 16 + t16] =
                    f2bf(o[mt][nt][r] * inv);
        }
    }
}

// ---------------------------------------------------------------------------
extern "C" void kernel_launch(void* const* d_in, const int* in_sizes, int n_in,
                              void* d_out, int out_size, void* d_ws, size_t ws_size,
                              hipStream_t stream) {
    const float* x  = (const float*)d_in[0];
    // d_in[1] = cancer_type (unused: bias_emb/keymod_emb cancel in softmax)
    const unsigned char* mask = (const unsigned char*)d_in[2];
    const float* wq = (const float*)d_in[3];
    const float* bq = (const float*)d_in[4];
    const float* wk = (const float*)d_in[5];
    const float* bk = (const float*)d_in[6];
    const float* wv = (const float*)d_in[7];
    const float* bv = (const float*)d_in[8];
    const float* wo = (const float*)d_in[9];
    const float* bo = (const float*)d_in[10];

    char* ws = (char*)d_ws;
    u16* xb  = (u16*)(ws);                      // 8 MB; reused as AOg after QKV gemm
    u16* wqb = (u16*)(ws + (8u << 20));
    u16* wkb = (u16*)(ws + (8u << 20) + (512u << 10));
    u16* wvb = (u16*)(ws + (8u << 20) + (1024u << 10));
    u16* wob = (u16*)(ws + (8u << 20) + (1536u << 10));
    u16* Qg  = (u16*)(ws + (10u << 20));
    u16* Kg  = (u16*)(ws + (18u << 20));
    u16* Vtg = (u16*)(ws + (26u << 20));
    u16* AOg = xb;                              // alias: xb dead after QKV gemm

    cvt_all<<<5120, 256, 0, stream>>>(x, wq, wk, wv, wo, xb, wqb, wkb, wvb, wob);

    gemm_mfma<<<dim3(TOK / 128, HID / 128, 3), 256, 0, stream>>>(
        xb, wqb, wkb, wvb, bq, bk, bv, Qg, Kg, Vtg, 1);

    flash_mfma<<<dim3(N_ / 128, B_ * NH), 256, 0, stream>>>(Qg, Kg, Vtg, mask, AOg);

    gemm_mfma<<<dim3(TOK / 128, HID / 128, 1), 256, 0, stream>>>(
        AOg, wob, wob, wob, bo, bo, bo, d_out, d_out, d_out, 0);
}